// Round 7
// baseline (279.555 us; speedup 1.0000x reference)
//
#include <hip/hip_runtime.h>

// Problem constants
#define G_GRAPHS 1024
#define N_NODES  40
#define M_EDGES  780          // N*(N-1)/2
#define NUM_NODES (G_GRAPHS * N_NODES)          // 40960
#define H_ELEMS  (NUM_NODES * 64)               // 2621440
#define X_STRIDE 160
#define X_PER_G  25600
#define SLOPE 0.1f

#define PACK_PER_MLP 9216     // W0(4096) + W1(4096) + W2(1024) bf16 elems

typedef __bf16 bf16x8 __attribute__((ext_vector_type(8)));
typedef unsigned short us8 __attribute__((ext_vector_type(8)));
typedef float f32x4 __attribute__((ext_vector_type(4)));

__device__ __forceinline__ float lrelu(float v) { return fmaxf(v, SLOPE * v); }
__device__ __forceinline__ unsigned short f2bf(float x) {
    __bf16 b = (__bf16)x;                       // RNE convert
    return __builtin_bit_cast(unsigned short, b);
}
__device__ __forceinline__ unsigned int pk2bf(float a, float b) {
    return (unsigned int)f2bf(a) | ((unsigned int)f2bf(b) << 16);
}

// ---------------------------------------------------------------------------
// K0: pack MLP weights (bf16) in d_ws. Layout serves the A-frag role:
// element for lane l, reg j, tile (mt,kt) of W^T is
// W[kt*32 + ((l>>4)&3)*8 + j][mt*16 + (l&15)]  -> linear ((mt*2+kt)*64+l)*8+j.
// W2 padded 10->16 cols (zeros). [0..9215] edge MLP, [9216..18431] node MLP.
// ---------------------------------------------------------------------------
__global__ __launch_bounds__(256) void k_prep(const float* __restrict__ We0,
                                              const float* __restrict__ We1,
                                              const float* __restrict__ We2,
                                              const float* __restrict__ Wn0,
                                              const float* __restrict__ Wn1,
                                              const float* __restrict__ Wn2,
                                              unsigned short* __restrict__ wp) {
    int t = blockIdx.x * 256 + threadIdx.x;     // 0..18431 (72 blocks)
    int mlp = t / PACK_PER_MLP;
    int o = t - mlp * PACK_PER_MLP;
    const float* W0 = mlp ? Wn0 : We0;
    const float* W1 = mlp ? Wn1 : We1;
    const float* W2 = mlp ? Wn2 : We2;
    float val;
    if (o < 8192) {
        const float* W = (o < 4096) ? W0 : W1;
        int idx = o & 4095;
        int j = idx & 7, l = (idx >> 3) & 63, tt = idx >> 9;   // tt = mt*2+kt
        int kt = tt & 1, mt = tt >> 1;
        int k = kt * 32 + ((l >> 4) & 3) * 8 + j;
        int m = mt * 16 + (l & 15);
        val = W[k * 64 + m];
    } else {
        int idx = o - 8192;                      // 0..1023, mt=0 only
        int j = idx & 7, l = (idx >> 3) & 63, kt = idx >> 9;
        int k = kt * 32 + ((l >> 4) & 3) * 8 + j;
        int m = l & 15;
        val = (m < 10) ? W2[k * 10 + m] : 0.f;
    }
    wp[mlp * PACK_PER_MLP + o] = f2bf(val);
}

// ---------------------------------------------------------------------------
// MLP chunk machinery. Round-7: SINGLE chain per wave (8 waves/block).
// TLP (4 waves/SIMD) replaces the round-5 2-chain ILP (same 4 independent
// chains per SIMD, but HW-scheduled + covers GCN/sweep phases too).
// Memory path (sEP arena + coalesced sweep) byte-identical to rounds 5/6
// (FETCH 1.8 MB / WRITE 112.6 MB measured ideal).
// ---------------------------------------------------------------------------
struct ChunkRegs {
    bf16x8 A1[4][2];
    bf16x8 A2[4][2];
    bf16x8 A3[2];
    float4 bv0[4];
    float4 bv1[4];
    float  bz[4];
};

__device__ __forceinline__ void run_chunk(int R0, int w, int l,
                                          const float4* sh4,
                                          unsigned short* sB,
                                          float* sEP,
                                          const unsigned short* sIJ,
                                          const ChunkRegs& cr) {
    const int nl = l & 15;
    const int rq = (l >> 4) & 3;
    const int rl = l >> 1;            // row within wave's 32-row slice
    const int hf2 = l & 1;            // feature half
    const int row = R0 + rl;

    const bool is_e = (row < 780);
    const bool is_n = (row >= 800 && row < 840);
    int ii = 0, jj = 0;
    if (is_e) {
        unsigned short e = sIJ[row];
        ii = e >> 8; jj = e & 255;
    } else if (is_n) {
        ii = jj = row - 800;
    }                                  // else dummy row

    // ---- E build: row, features [hf2*32, hf2*32+32) -> sB (swizzled) ----
    {
        unsigned short tmp[32];
#pragma unroll
        for (int q = 0; q < 8; q++) {
            int u = hf2 * 8 + q;
            float4 a = sh4[ii * 16 + (u ^ ((ii & 7) << 1))];
            if (is_e) {
                float4 bq = sh4[jj * 16 + (u ^ ((jj & 7) << 1))];
                a.x += bq.x; a.y += bq.y; a.z += bq.z; a.w += bq.w;
            }
            tmp[4 * q + 0] = f2bf(a.x); tmp[4 * q + 1] = f2bf(a.y);
            tmp[4 * q + 2] = f2bf(a.z); tmp[4 * q + 3] = f2bf(a.w);
        }
        int r_sb = 32 * w + rl;        // 0..255 (8 waves x 32 rows)
#pragma unroll
        for (int q = 0; q < 4; q++) {
            int cs = (hf2 * 4 + q) ^ (r_sb & 7);
            *(us8*)((char*)sB + r_sb * 128 + cs * 16) = *(const us8*)(tmp + 8 * q);
        }
    }

    // B-frag read / Z store helpers (same swizzle as rounds 0-6)
    auto ZB = [&](int nt, int kt) -> bf16x8 {
        int node = 32 * w + nt * 16 + nl;
        int cs = (kt * 4 + rq) ^ (node & 7);
        return __builtin_bit_cast(bf16x8,
            *(const us8*)((const char*)sB + node * 128 + cs * 16));
    };
    auto zstore = [&](int mt, int nt, const f32x4& v) {
        int node = 32 * w + nt * 16 + nl;
        int cs = (mt * 2 + (rq >> 1)) ^ (node & 7);
        uint2 u = make_uint2(pk2bf(v[0], v[1]), pk2bf(v[2], v[3]));
        *(uint2*)((char*)sB + node * 128 + cs * 16 + (rq & 1) * 8) = u;
    };

    auto gemm_layer = [&](const bf16x8 A[4][2], const float4* bv) {
        bf16x8 B[2][2];
#pragma unroll
        for (int nt = 0; nt < 2; nt++)
#pragma unroll
            for (int kt = 0; kt < 2; kt++) B[nt][kt] = ZB(nt, kt);
#pragma unroll
        for (int mt = 0; mt < 4; mt++) {
            float4 b = bv[mt];
#pragma unroll
            for (int nt = 0; nt < 2; nt++) {
                f32x4 acc = (f32x4){b.x, b.y, b.z, b.w};   // bias as C-input
                acc = __builtin_amdgcn_mfma_f32_16x16x32_bf16(A[mt][0], B[nt][0], acc, 0, 0, 0);
                acc = __builtin_amdgcn_mfma_f32_16x16x32_bf16(A[mt][1], B[nt][1], acc, 0, 0, 0);
                f32x4 z;
                z[0] = lrelu(acc[0]); z[1] = lrelu(acc[1]);
                z[2] = lrelu(acc[2]); z[3] = lrelu(acc[3]);
                zstore(mt, nt, z);
            }
        }
    };

    // ---- GEMM1 (Z1), GEMM2 (Z2): in place ----
    gemm_layer(cr.A1, cr.bv0);
    gemm_layer(cr.A2, cr.bv1);

    // ---- GEMM3: EP -> sEP (f32, stride 10) ----
    {
        bf16x8 B[2][2];
#pragma unroll
        for (int nt = 0; nt < 2; nt++)
#pragma unroll
            for (int kt = 0; kt < 2; kt++) B[nt][kt] = ZB(nt, kt);
#pragma unroll
        for (int nt = 0; nt < 2; nt++) {
            f32x4 acc = (f32x4){cr.bz[0], cr.bz[1], cr.bz[2], cr.bz[3]};
            acc = __builtin_amdgcn_mfma_f32_16x16x32_bf16(cr.A3[0], B[nt][0], acc, 0, 0, 0);
            acc = __builtin_amdgcn_mfma_f32_16x16x32_bf16(cr.A3[1], B[nt][1], acc, 0, 0, 0);
            int rowe = R0 + nt * 16 + nl;
            bool valid = (rowe < 780) || (rowe >= 800 && rowe < 840);
            if (valid && rq < 3) {
                int epr = (rowe < 780) ? rowe : rowe - 20;   // nodes -> 780..819
                float* p = sEP + epr * 10 + rq * 4;
                *(float2*)p = make_float2(acc[0], acc[1]);
                if (rq < 2)
                    *(float2*)(p + 2) = make_float2(acc[2], acc[3]);
            }
        }
    }
}

// ---------------------------------------------------------------------------
// K1 (fused): GCN + MLP + coalesced X sweep, one graph per 512-THREAD block.
// LDS arena (77,368 B, 2 blocks/CU -> 16 waves/CU = 4 waves/SIMD, 2x round 6):
//   [0,     10240)  sh   : final h, 40x64 f32, swizzled | GCN: h0@0
//   [10240, 43008)  sB   : 256x64 bf16 GEMM ping (8 waves x 4 KB slices)
//                          | GCN: buf@10240, h1@20480, h2@25600
//   [43008, 75808)  sEP  : 820x10 f32 MLP outputs       | GCN: P@43008
//   [75808, 77368)  sIJ  : edge (i<<8|j) decode table
// Chunk map: wave w (0..7) takes chunks {w, w+8, w+16, w+24} -> node chunks
// 25/26 are waves 1/2's LAST chunk (loadW-overwrite trick); dummy 27 wave 3.
// ---------------------------------------------------------------------------
__global__ __launch_bounds__(512, 4) void k_fused(const float* __restrict__ x,
                                                  const float* __restrict__ Wg0,
                                                  const float* __restrict__ bg0,
                                                  const float* __restrict__ Wg1,
                                                  const float* __restrict__ bg1,
                                                  const float* __restrict__ Wg2,
                                                  const float* __restrict__ bg2,
                                                  const unsigned short* __restrict__ wp,
                                                  const float* __restrict__ be0,
                                                  const float* __restrict__ be1,
                                                  const float* __restrict__ be2,
                                                  const float* __restrict__ bn0,
                                                  const float* __restrict__ bn1,
                                                  const float* __restrict__ bn2,
                                                  float* __restrict__ hout,
                                                  float* __restrict__ X) {
    __shared__ __align__(16) char smem[77368];
    float* sh           = (float*)smem;                      // [0,10240)
    unsigned short* sB  = (unsigned short*)(smem + 10240);   // [10240,43008)
    float* sEP          = (float*)(smem + 43008);            // [43008,75808)
    unsigned short* sIJ = (unsigned short*)(smem + 75808);   // [75808,77368)
    // GCN-phase aliases
    float* h0  = (float*)smem;                               // [0,960)
    float* buf = (float*)(smem + 10240);                     // [10240,20480)
    float* h1  = (float*)(smem + 20480);                     // [20480,25600)
    float* h2  = (float*)(smem + 25600);                     // [25600,30720)
    float* P   = (float*)(smem + 43008);                     // [43008,45056)

    const int g = blockIdx.x;
    const int tid = threadIdx.x;                             // 0..511
    const int l = tid & 63;
    const int w = tid >> 6;                                  // wave 0..7
    const float inv39 = 1.0f / 39.0f;
    const int c32 = tid & 31;
    const int c64 = tid & 63;
    const int rq = (l >> 4) & 3;

    // ---- build edge decode table (once per block; covered by GCN bar #1) --
    for (int m = tid; m < 780; m += 512) {
        float tq = 6241.0f - 8.0f * (float)m;      // exact in fp32
        int i0 = (int)(0.5f * (79.0f - sqrtf(tq)));
        i0 = min(38, max(0, i0));
        int cum = 39 * i0 - ((i0 * (i0 - 1)) >> 1);
        if (cum > m) { --i0; cum = 39 * i0 - ((i0 * (i0 - 1)) >> 1); }
        else if (m - cum >= 39 - i0) { cum += 39 - i0; ++i0; }
        int jj = i0 + 1 + (m - cum);
        sIJ[m] = (unsigned short)((i0 << 8) | jj);
    }

    // =========================== GCN phase ===========================
    {
        float w0c[6], w1c[32], w2c[32];
#pragma unroll
        for (int f = 0; f < 6; f++)  w0c[f] = Wg0[f * 32 + c32];
#pragma unroll
        for (int m = 0; m < 32; m++) w1c[m] = Wg1[m * 32 + c32];
#pragma unroll
        for (int m = 0; m < 32; m++) w2c[m] = Wg2[m * 64 + c64];
        const float b0c = bg0[c32];
        const float b1c = bg1[c32];
        const float b2c = bg2[c64];

        if (tid < 240) {
            int n = tid / 6, f = tid - n * 6;
            h0[tid] = x[(g * N_NODES + n) * 16 + f];
        }
        __syncthreads();                                      // bar 1

        // ---- layer 0: buf = h0 @ Wg0 (1280 items, stride 512) ----
        for (int idx = tid; idx < N_NODES * 32; idx += 512) {
            int n = idx >> 5;
            float s = 0.f;
#pragma unroll
            for (int f = 0; f < 6; f++) s += h0[n * 6 + f] * w0c[f];
            buf[idx] = s;
        }
        __syncthreads();                                      // bar 2
        if (tid < 256) { int grp = tid >> 5; float s = 0.f;
#pragma unroll
          for (int n = grp * 5; n < grp * 5 + 5; n++) s += buf[n * 32 + c32];
          P[grp * 32 + c32] = s; }
        __syncthreads();                                      // bar 3
        { float s0 = 0.f;
#pragma unroll
          for (int grp = 0; grp < 8; grp++) s0 += P[grp * 32 + c32];
          for (int idx = tid; idx < N_NODES * 32; idx += 512)
              h1[idx] = lrelu((s0 - buf[idx]) * inv39 + b0c); }
        __syncthreads();                                      // bar 4

        // ---- layer 1: buf = h1 @ Wg1 ----
        for (int idx = tid; idx < N_NODES * 32; idx += 512) {
            int n = idx >> 5;
            const float4* hp = (const float4*)(h1 + n * 32);
            float s = 0.f;
#pragma unroll
            for (int q = 0; q < 8; q++) {
                float4 hv = hp[q];
                s += hv.x * w1c[4 * q + 0] + hv.y * w1c[4 * q + 1]
                   + hv.z * w1c[4 * q + 2] + hv.w * w1c[4 * q + 3];
            }
            buf[idx] = s;
        }
        __syncthreads();                                      // bar 5
        if (tid < 256) { int grp = tid >> 5; float s = 0.f;
#pragma unroll
          for (int n = grp * 5; n < grp * 5 + 5; n++) s += buf[n * 32 + c32];
          P[grp * 32 + c32] = s; }
        __syncthreads();                                      // bar 6
        { float s0 = 0.f;
#pragma unroll
          for (int grp = 0; grp < 8; grp++) s0 += P[grp * 32 + c32];
          for (int idx = tid; idx < N_NODES * 32; idx += 512)
              h2[idx] = lrelu((s0 - buf[idx]) * inv39 + b1c); }
        __syncthreads();                                      // bar 7

        // ---- layer 2: buf = h2 @ Wg2 (2560 items, stride 512) ----
        for (int idx = tid; idx < N_NODES * 64; idx += 512) {
            int n = idx >> 6;
            const float4* hp = (const float4*)(h2 + n * 32);
            float s = 0.f;
#pragma unroll
            for (int q = 0; q < 8; q++) {
                float4 hv = hp[q];
                s += hv.x * w2c[4 * q + 0] + hv.y * w2c[4 * q + 1]
                   + hv.z * w2c[4 * q + 2] + hv.w * w2c[4 * q + 3];
            }
            buf[idx] = s;
        }
        __syncthreads();                                      // bar 8
        { int grp = tid >> 6; float s = 0.f;                  // 8 grp x 5 rows
#pragma unroll
          for (int n = grp * 5; n < grp * 5 + 5; n++) s += buf[n * 64 + c64];
          P[grp * 64 + c64] = s; }
        __syncthreads();                                      // bar 9

        // ---- epilogue: write hout (global) + sh (LDS, swizzled) ----
        // (P @43008 outside sh -> no race; clobbers only dead h0 region)
        { float s0 = 0.f;
#pragma unroll
          for (int grp = 0; grp < 8; grp++) s0 += P[grp * 64 + c64];
          for (int idx = tid; idx < N_NODES * 64; idx += 512) {
              float v = (s0 - buf[idx]) * inv39 + b2c;
              hout[g * N_NODES * 64 + idx] = v;
              int n = idx >> 6;
              int u = c64 >> 2;
              int us = u ^ ((n & 7) << 1);
              sh[n * 64 + us * 4 + (c64 & 3)] = v;
          } }
    }
    __syncthreads();   // bar 10: sh + sIJ ready; GCN scratch dead

    // =========================== MLP phase ===========================
    const float4* sh4 = (const float4*)sh;

    auto WA = [&](const unsigned short* base, int mt, int kt) -> bf16x8 {
        return __builtin_bit_cast(bf16x8,
            *(const us8*)(base + ((mt * 2 + kt) * 64 + l) * 8));
    };
    auto loadW = [&](ChunkRegs& cr, const unsigned short* wb,
                     const float* B0, const float* B1, const float* B2) {
#pragma unroll
        for (int mt = 0; mt < 4; mt++) {
#pragma unroll
            for (int kt = 0; kt < 2; kt++) {
                cr.A1[mt][kt] = WA(wb, mt, kt);
                cr.A2[mt][kt] = WA(wb + 4096, mt, kt);
            }
            cr.bv0[mt] = *(const float4*)(B0 + mt * 16 + rq * 4);
            cr.bv1[mt] = *(const float4*)(B1 + mt * 16 + rq * 4);
        }
        cr.A3[0] = WA(wb + 8192, 0, 0);
        cr.A3[1] = WA(wb + 8192, 0, 1);
#pragma unroll
        for (int k = 0; k < 4; k++) {
            int f = rq * 4 + k;
            cr.bz[k] = (f < 10) ? B2[f] : 0.f;
        }
    };

    ChunkRegs ce;
    loadW(ce, wp, be0, be1, be2);            // edge MLP weights

    // chunk loop: wave-local, no barriers. Chunks 25 (wave 1) and 26 (wave 2)
    // are those waves' LAST chunk -> overwrite ce with node weights in place.
    // Chunk 27 (wave 3) is all-dummy: runs with edge weights, stores nothing.
    for (int c = w; c < 28; c += 8) {
        if (c == 25 || c == 26)
            loadW(ce, wp + PACK_PER_MLP, bn0, bn1, bn2);
        run_chunk(32 * c, w, l, sh4, sB, sEP, sIJ, ce);
    }

    __syncthreads();   // all EP rows ready

    // ---- X sweep: thread owns whole 4x4 blocks; coalesced stores ----
    float* Xg = X + g * X_PER_G;
#pragma unroll
    for (int k = 0; k < 4; k++) {
        int b = k * 512 + tid;
        if (b < 1600) {
            int bi = b / 40;
            int bj = b - bi * 40;
            int ridx;
            if (bi == bj) {
                ridx = 780 + bi;
            } else {
                int mn = min(bi, bj), mx = max(bi, bj);
                ridx = 39 * mn - ((mn * (mn - 1)) >> 1) + (mx - mn - 1);
            }
            const float* ep = sEP + ridx * 10;
            float2 e0 = *(const float2*)(ep + 0);
            float2 e1 = *(const float2*)(ep + 2);
            float2 e2 = *(const float2*)(ep + 4);
            float2 e3 = *(const float2*)(ep + 6);
            float2 e4 = *(const float2*)(ep + 8);
            float f0 = e0.x, f1 = e0.y, f2 = e1.x, f3 = e1.y;
            float f4 = e2.x, f5 = e2.y, f6 = e3.x, f7 = e3.y;
            float f8 = e4.x, f9 = e4.y;
            float4 r0 = make_float4(f0, f1, f2, f3);
            float4 r1 = make_float4(f1, f4, f5, f6);
            float4 r2 = make_float4(f2, f5, f7, f8);
            float4 r3 = make_float4(f3, f6, f8, f9);
            float* p = Xg + (4 * bi) * X_STRIDE + 4 * bj;
            *(float4*)(p + 0 * X_STRIDE) = r0;
            *(float4*)(p + 1 * X_STRIDE) = r1;
            *(float4*)(p + 2 * X_STRIDE) = r2;
            *(float4*)(p + 3 * X_STRIDE) = r3;
        }
    }
}

// ---------------------------------------------------------------------------
// Launch
// ---------------------------------------------------------------------------
extern "C" void kernel_launch(void* const* d_in, const int* in_sizes, int n_in,
                              void* d_out, int out_size, void* d_ws, size_t ws_size,
                              hipStream_t stream) {
    const float* x   = (const float*)d_in[0];
    const float* Wg0 = (const float*)d_in[4];
    const float* bg0 = (const float*)d_in[5];
    const float* Wg1 = (const float*)d_in[6];
    const float* bg1 = (const float*)d_in[7];
    const float* Wg2 = (const float*)d_in[8];
    const float* bg2 = (const float*)d_in[9];
    const float* Wn0 = (const float*)d_in[10];
    const float* bn0 = (const float*)d_in[11];
    const float* Wn1 = (const float*)d_in[12];
    const float* bn1 = (const float*)d_in[13];
    const float* Wn2 = (const float*)d_in[14];
    const float* bn2 = (const float*)d_in[15];
    const float* We0 = (const float*)d_in[16];
    const float* be0 = (const float*)d_in[17];
    const float* We1 = (const float*)d_in[18];
    const float* be1 = (const float*)d_in[19];
    const float* We2 = (const float*)d_in[20];
    const float* be2 = (const float*)d_in[21];

    float* hout = (float*)d_out;            // h: 40960 x 64 fp32
    float* X    = hout + H_ELEMS;           // X: 1024 x 160 x 160 fp32
    unsigned short* wp = (unsigned short*)d_ws;  // 18432 bf16 packed weights

    k_prep<<<72, 256, 0, stream>>>(We0, We1, We2, Wn0, Wn1, Wn2, wp);
    k_fused<<<G_GRAPHS, 512, 0, stream>>>(x, Wg0, bg0, Wg1, bg1, Wg2, bg2,
                                          wp, be0, be1, be2, bn0, bn1, bn2,
                                          hout, X);
}

// Round 8
// 220.366 us; speedup vs baseline: 1.2686x; 1.2686x over previous
//
#include <hip/hip_runtime.h>

// Problem constants
#define G_GRAPHS 1024
#define N_NODES  40
#define M_EDGES  780          // N*(N-1)/2
#define NUM_NODES (G_GRAPHS * N_NODES)          // 40960
#define H_ELEMS  (NUM_NODES * 64)               // 2621440
#define X_STRIDE 160
#define X_PER_G  25600
#define SLOPE 0.1f

#define PACK_PER_MLP 9216     // W0(4096) + W1(4096) + W2(1024) bf16 elems

typedef __bf16 bf16x8 __attribute__((ext_vector_type(8)));
typedef unsigned short us8 __attribute__((ext_vector_type(8)));
typedef float f32x4 __attribute__((ext_vector_type(4)));

__device__ __forceinline__ float lrelu(float v) { return fmaxf(v, SLOPE * v); }
__device__ __forceinline__ unsigned short f2bf(float x) {
    __bf16 b = (__bf16)x;                       // RNE convert
    return __builtin_bit_cast(unsigned short, b);
}
__device__ __forceinline__ unsigned int pk2bf(float a, float b) {
    return (unsigned int)f2bf(a) | ((unsigned int)f2bf(b) << 16);
}

// ---------------------------------------------------------------------------
// K0: pack MLP weights (bf16) in d_ws. Layout serves the A-frag role:
// element for lane l, reg j, tile (mt,kt) of W^T is
// W[kt*32 + ((l>>4)&3)*8 + j][mt*16 + (l&15)]  -> linear ((mt*2+kt)*64+l)*8+j.
// W2 padded 10->16 cols (zeros). [0..9215] edge MLP, [9216..18431] node MLP.
// ---------------------------------------------------------------------------
__global__ __launch_bounds__(256) void k_prep(const float* __restrict__ We0,
                                              const float* __restrict__ We1,
                                              const float* __restrict__ We2,
                                              const float* __restrict__ Wn0,
                                              const float* __restrict__ Wn1,
                                              const float* __restrict__ Wn2,
                                              unsigned short* __restrict__ wp) {
    int t = blockIdx.x * 256 + threadIdx.x;     // 0..18431 (72 blocks)
    int mlp = t / PACK_PER_MLP;
    int o = t - mlp * PACK_PER_MLP;
    const float* W0 = mlp ? Wn0 : We0;
    const float* W1 = mlp ? Wn1 : We1;
    const float* W2 = mlp ? Wn2 : We2;
    float val;
    if (o < 8192) {
        const float* W = (o < 4096) ? W0 : W1;
        int idx = o & 4095;
        int j = idx & 7, l = (idx >> 3) & 63, tt = idx >> 9;   // tt = mt*2+kt
        int kt = tt & 1, mt = tt >> 1;
        int k = kt * 32 + ((l >> 4) & 3) * 8 + j;
        int m = mt * 16 + (l & 15);
        val = W[k * 64 + m];
    } else {
        int idx = o - 8192;                      // 0..1023, mt=0 only
        int j = idx & 7, l = (idx >> 3) & 63, kt = idx >> 9;
        int k = kt * 32 + ((l >> 4) & 3) * 8 + j;
        int m = l & 15;
        val = (m < 10) ? W2[k * 10 + m] : 0.f;
    }
    wp[mlp * PACK_PER_MLP + o] = f2bf(val);
}

// ---------------------------------------------------------------------------
// MLP chunk machinery. Round-8 = round-7 structure with the spill bug fixed:
// __launch_bounds__(512, 2) caps VGPR at 256 (allocator uses its natural
// ~112, same body as round 6), so ChunkRegs stays in registers. Actual
// occupancy = min(LDS: 2 blocks, VGPR<=128: 4 waves/SIMD) = 16 waves/CU.
// Round-7's (512,4) forced VGPR=64 -> whole weight set spilled to scratch
// (FETCH 166 MB / WRITE 309 MB of pure spill traffic).
// ---------------------------------------------------------------------------
struct ChunkRegs {
    bf16x8 A1[4][2];
    bf16x8 A2[4][2];
    bf16x8 A3[2];
    float4 bv0[4];
    float4 bv1[4];
    float  bz[4];
};

__device__ __forceinline__ void run_chunk(int R0, int w, int l,
                                          const float4* sh4,
                                          unsigned short* sB,
                                          float* sEP,
                                          const unsigned short* sIJ,
                                          const ChunkRegs& cr) {
    const int nl = l & 15;
    const int rq = (l >> 4) & 3;
    const int rl = l >> 1;            // row within wave's 32-row slice
    const int hf2 = l & 1;            // feature half
    const int row = R0 + rl;

    const bool is_e = (row < 780);
    const bool is_n = (row >= 800 && row < 840);
    int ii = 0, jj = 0;
    if (is_e) {
        unsigned short e = sIJ[row];
        ii = e >> 8; jj = e & 255;
    } else if (is_n) {
        ii = jj = row - 800;
    }                                  // else dummy row

    // ---- E build: row, features [hf2*32, hf2*32+32) -> sB (swizzled) ----
    {
        unsigned short tmp[32];
#pragma unroll
        for (int q = 0; q < 8; q++) {
            int u = hf2 * 8 + q;
            float4 a = sh4[ii * 16 + (u ^ ((ii & 7) << 1))];
            if (is_e) {
                float4 bq = sh4[jj * 16 + (u ^ ((jj & 7) << 1))];
                a.x += bq.x; a.y += bq.y; a.z += bq.z; a.w += bq.w;
            }
            tmp[4 * q + 0] = f2bf(a.x); tmp[4 * q + 1] = f2bf(a.y);
            tmp[4 * q + 2] = f2bf(a.z); tmp[4 * q + 3] = f2bf(a.w);
        }
        int r_sb = 32 * w + rl;        // 0..255 (8 waves x 32 rows)
#pragma unroll
        for (int q = 0; q < 4; q++) {
            int cs = (hf2 * 4 + q) ^ (r_sb & 7);
            *(us8*)((char*)sB + r_sb * 128 + cs * 16) = *(const us8*)(tmp + 8 * q);
        }
    }

    // B-frag read / Z store helpers (same swizzle as rounds 0-7)
    auto ZB = [&](int nt, int kt) -> bf16x8 {
        int node = 32 * w + nt * 16 + nl;
        int cs = (kt * 4 + rq) ^ (node & 7);
        return __builtin_bit_cast(bf16x8,
            *(const us8*)((const char*)sB + node * 128 + cs * 16));
    };
    auto zstore = [&](int mt, int nt, const f32x4& v) {
        int node = 32 * w + nt * 16 + nl;
        int cs = (mt * 2 + (rq >> 1)) ^ (node & 7);
        uint2 u = make_uint2(pk2bf(v[0], v[1]), pk2bf(v[2], v[3]));
        *(uint2*)((char*)sB + node * 128 + cs * 16 + (rq & 1) * 8) = u;
    };

    auto gemm_layer = [&](const bf16x8 A[4][2], const float4* bv) {
        bf16x8 B[2][2];
#pragma unroll
        for (int nt = 0; nt < 2; nt++)
#pragma unroll
            for (int kt = 0; kt < 2; kt++) B[nt][kt] = ZB(nt, kt);
#pragma unroll
        for (int mt = 0; mt < 4; mt++) {
            float4 b = bv[mt];
#pragma unroll
            for (int nt = 0; nt < 2; nt++) {
                f32x4 acc = (f32x4){b.x, b.y, b.z, b.w};   // bias as C-input
                acc = __builtin_amdgcn_mfma_f32_16x16x32_bf16(A[mt][0], B[nt][0], acc, 0, 0, 0);
                acc = __builtin_amdgcn_mfma_f32_16x16x32_bf16(A[mt][1], B[nt][1], acc, 0, 0, 0);
                f32x4 z;
                z[0] = lrelu(acc[0]); z[1] = lrelu(acc[1]);
                z[2] = lrelu(acc[2]); z[3] = lrelu(acc[3]);
                zstore(mt, nt, z);
            }
        }
    };

    // ---- GEMM1 (Z1), GEMM2 (Z2): in place ----
    gemm_layer(cr.A1, cr.bv0);
    gemm_layer(cr.A2, cr.bv1);

    // ---- GEMM3: EP -> sEP (f32, stride 10) ----
    {
        bf16x8 B[2][2];
#pragma unroll
        for (int nt = 0; nt < 2; nt++)
#pragma unroll
            for (int kt = 0; kt < 2; kt++) B[nt][kt] = ZB(nt, kt);
#pragma unroll
        for (int nt = 0; nt < 2; nt++) {
            f32x4 acc = (f32x4){cr.bz[0], cr.bz[1], cr.bz[2], cr.bz[3]};
            acc = __builtin_amdgcn_mfma_f32_16x16x32_bf16(cr.A3[0], B[nt][0], acc, 0, 0, 0);
            acc = __builtin_amdgcn_mfma_f32_16x16x32_bf16(cr.A3[1], B[nt][1], acc, 0, 0, 0);
            int rowe = R0 + nt * 16 + nl;
            bool valid = (rowe < 780) || (rowe >= 800 && rowe < 840);
            if (valid && rq < 3) {
                int epr = (rowe < 780) ? rowe : rowe - 20;   // nodes -> 780..819
                float* p = sEP + epr * 10 + rq * 4;
                *(float2*)p = make_float2(acc[0], acc[1]);
                if (rq < 2)
                    *(float2*)(p + 2) = make_float2(acc[2], acc[3]);
            }
        }
    }
}

// ---------------------------------------------------------------------------
// K1 (fused): GCN + MLP + coalesced X sweep, one graph per 512-THREAD block.
// LDS arena (77,368 B, 2 blocks/CU -> 16 waves/CU = 4 waves/SIMD):
//   [0,     10240)  sh   : final h, 40x64 f32, swizzled | GCN: h0@0
//   [10240, 43008)  sB   : 256x64 bf16 GEMM ping (8 waves x 4 KB slices)
//                          | GCN: buf@10240, h1@20480, h2@25600
//   [43008, 75808)  sEP  : 820x10 f32 MLP outputs       | GCN: P@43008
//   [75808, 77368)  sIJ  : edge (i<<8|j) decode table
// Chunk map: wave w (0..7) takes chunks {w, w+8, w+16, w+24} -> node chunks
// 25/26 are waves 1/2's LAST chunk (loadW-overwrite trick); dummy 27 wave 3.
// launch_bounds(512,2): VGPR cap 256, allocator uses ~112 (round-6 measured)
// -> no spills; 2nd resident block comes from the LDS/VGPR limits, not the
// bound. ((512,4) forced VGPR=64 -> catastrophic ChunkRegs spill, round 7.)
// ---------------------------------------------------------------------------
__global__ __launch_bounds__(512, 2) void k_fused(const float* __restrict__ x,
                                                  const float* __restrict__ Wg0,
                                                  const float* __restrict__ bg0,
                                                  const float* __restrict__ Wg1,
                                                  const float* __restrict__ bg1,
                                                  const float* __restrict__ Wg2,
                                                  const float* __restrict__ bg2,
                                                  const unsigned short* __restrict__ wp,
                                                  const float* __restrict__ be0,
                                                  const float* __restrict__ be1,
                                                  const float* __restrict__ be2,
                                                  const float* __restrict__ bn0,
                                                  const float* __restrict__ bn1,
                                                  const float* __restrict__ bn2,
                                                  float* __restrict__ hout,
                                                  float* __restrict__ X) {
    __shared__ __align__(16) char smem[77368];
    float* sh           = (float*)smem;                      // [0,10240)
    unsigned short* sB  = (unsigned short*)(smem + 10240);   // [10240,43008)
    float* sEP          = (float*)(smem + 43008);            // [43008,75808)
    unsigned short* sIJ = (unsigned short*)(smem + 75808);   // [75808,77368)
    // GCN-phase aliases
    float* h0  = (float*)smem;                               // [0,960)
    float* buf = (float*)(smem + 10240);                     // [10240,20480)
    float* h1  = (float*)(smem + 20480);                     // [20480,25600)
    float* h2  = (float*)(smem + 25600);                     // [25600,30720)
    float* P   = (float*)(smem + 43008);                     // [43008,45056)

    const int g = blockIdx.x;
    const int tid = threadIdx.x;                             // 0..511
    const int l = tid & 63;
    const int w = tid >> 6;                                  // wave 0..7
    const float inv39 = 1.0f / 39.0f;
    const int c32 = tid & 31;
    const int c64 = tid & 63;
    const int rq = (l >> 4) & 3;

    // ---- build edge decode table (once per block; covered by GCN bar #1) --
    for (int m = tid; m < 780; m += 512) {
        float tq = 6241.0f - 8.0f * (float)m;      // exact in fp32
        int i0 = (int)(0.5f * (79.0f - sqrtf(tq)));
        i0 = min(38, max(0, i0));
        int cum = 39 * i0 - ((i0 * (i0 - 1)) >> 1);
        if (cum > m) { --i0; cum = 39 * i0 - ((i0 * (i0 - 1)) >> 1); }
        else if (m - cum >= 39 - i0) { cum += 39 - i0; ++i0; }
        int jj = i0 + 1 + (m - cum);
        sIJ[m] = (unsigned short)((i0 << 8) | jj);
    }

    // =========================== GCN phase ===========================
    {
        float w0c[6], w1c[32], w2c[32];
#pragma unroll
        for (int f = 0; f < 6; f++)  w0c[f] = Wg0[f * 32 + c32];
#pragma unroll
        for (int m = 0; m < 32; m++) w1c[m] = Wg1[m * 32 + c32];
#pragma unroll
        for (int m = 0; m < 32; m++) w2c[m] = Wg2[m * 64 + c64];
        const float b0c = bg0[c32];
        const float b1c = bg1[c32];
        const float b2c = bg2[c64];

        if (tid < 240) {
            int n = tid / 6, f = tid - n * 6;
            h0[tid] = x[(g * N_NODES + n) * 16 + f];
        }
        __syncthreads();                                      // bar 1

        // ---- layer 0: buf = h0 @ Wg0 (1280 items, stride 512) ----
        for (int idx = tid; idx < N_NODES * 32; idx += 512) {
            int n = idx >> 5;
            float s = 0.f;
#pragma unroll
            for (int f = 0; f < 6; f++) s += h0[n * 6 + f] * w0c[f];
            buf[idx] = s;
        }
        __syncthreads();                                      // bar 2
        if (tid < 256) { int grp = tid >> 5; float s = 0.f;
#pragma unroll
          for (int n = grp * 5; n < grp * 5 + 5; n++) s += buf[n * 32 + c32];
          P[grp * 32 + c32] = s; }
        __syncthreads();                                      // bar 3
        { float s0 = 0.f;
#pragma unroll
          for (int grp = 0; grp < 8; grp++) s0 += P[grp * 32 + c32];
          for (int idx = tid; idx < N_NODES * 32; idx += 512)
              h1[idx] = lrelu((s0 - buf[idx]) * inv39 + b0c); }
        __syncthreads();                                      // bar 4

        // ---- layer 1: buf = h1 @ Wg1 ----
        for (int idx = tid; idx < N_NODES * 32; idx += 512) {
            int n = idx >> 5;
            const float4* hp = (const float4*)(h1 + n * 32);
            float s = 0.f;
#pragma unroll
            for (int q = 0; q < 8; q++) {
                float4 hv = hp[q];
                s += hv.x * w1c[4 * q + 0] + hv.y * w1c[4 * q + 1]
                   + hv.z * w1c[4 * q + 2] + hv.w * w1c[4 * q + 3];
            }
            buf[idx] = s;
        }
        __syncthreads();                                      // bar 5
        if (tid < 256) { int grp = tid >> 5; float s = 0.f;
#pragma unroll
          for (int n = grp * 5; n < grp * 5 + 5; n++) s += buf[n * 32 + c32];
          P[grp * 32 + c32] = s; }
        __syncthreads();                                      // bar 6
        { float s0 = 0.f;
#pragma unroll
          for (int grp = 0; grp < 8; grp++) s0 += P[grp * 32 + c32];
          for (int idx = tid; idx < N_NODES * 32; idx += 512)
              h2[idx] = lrelu((s0 - buf[idx]) * inv39 + b1c); }
        __syncthreads();                                      // bar 7

        // ---- layer 2: buf = h2 @ Wg2 (2560 items, stride 512) ----
        for (int idx = tid; idx < N_NODES * 64; idx += 512) {
            int n = idx >> 6;
            const float4* hp = (const float4*)(h2 + n * 32);
            float s = 0.f;
#pragma unroll
            for (int q = 0; q < 8; q++) {
                float4 hv = hp[q];
                s += hv.x * w2c[4 * q + 0] + hv.y * w2c[4 * q + 1]
                   + hv.z * w2c[4 * q + 2] + hv.w * w2c[4 * q + 3];
            }
            buf[idx] = s;
        }
        __syncthreads();                                      // bar 8
        { int grp = tid >> 6; float s = 0.f;                  // 8 grp x 5 rows
#pragma unroll
          for (int n = grp * 5; n < grp * 5 + 5; n++) s += buf[n * 64 + c64];
          P[grp * 64 + c64] = s; }
        __syncthreads();                                      // bar 9

        // ---- epilogue: write hout (global) + sh (LDS, swizzled) ----
        // (P @43008 outside sh -> no race; clobbers only dead h0 region)
        { float s0 = 0.f;
#pragma unroll
          for (int grp = 0; grp < 8; grp++) s0 += P[grp * 64 + c64];
          for (int idx = tid; idx < N_NODES * 64; idx += 512) {
              float v = (s0 - buf[idx]) * inv39 + b2c;
              hout[g * N_NODES * 64 + idx] = v;
              int n = idx >> 6;
              int u = c64 >> 2;
              int us = u ^ ((n & 7) << 1);
              sh[n * 64 + us * 4 + (c64 & 3)] = v;
          } }
    }
    __syncthreads();   // bar 10: sh + sIJ ready; GCN scratch dead

    // =========================== MLP phase ===========================
    const float4* sh4 = (const float4*)sh;

    auto WA = [&](const unsigned short* base, int mt, int kt) -> bf16x8 {
        return __builtin_bit_cast(bf16x8,
            *(const us8*)(base + ((mt * 2 + kt) * 64 + l) * 8));
    };
    auto loadW = [&](ChunkRegs& cr, const unsigned short* wb,
                     const float* B0, const float* B1, const float* B2) {
#pragma unroll
        for (int mt = 0; mt < 4; mt++) {
#pragma unroll
            for (int kt = 0; kt < 2; kt++) {
                cr.A1[mt][kt] = WA(wb, mt, kt);
                cr.A2[mt][kt] = WA(wb + 4096, mt, kt);
            }
            cr.bv0[mt] = *(const float4*)(B0 + mt * 16 + rq * 4);
            cr.bv1[mt] = *(const float4*)(B1 + mt * 16 + rq * 4);
        }
        cr.A3[0] = WA(wb + 8192, 0, 0);
        cr.A3[1] = WA(wb + 8192, 0, 1);
#pragma unroll
        for (int k = 0; k < 4; k++) {
            int f = rq * 4 + k;
            cr.bz[k] = (f < 10) ? B2[f] : 0.f;
        }
    };

    ChunkRegs ce;
    loadW(ce, wp, be0, be1, be2);            // edge MLP weights

    // chunk loop: wave-local, no barriers. Chunks 25 (wave 1) and 26 (wave 2)
    // are those waves' LAST chunk -> overwrite ce with node weights in place.
    // Chunk 27 (wave 3) is all-dummy: runs with edge weights, stores nothing.
    for (int c = w; c < 28; c += 8) {
        if (c == 25 || c == 26)
            loadW(ce, wp + PACK_PER_MLP, bn0, bn1, bn2);
        run_chunk(32 * c, w, l, sh4, sB, sEP, sIJ, ce);
    }

    __syncthreads();   // all EP rows ready

    // ---- X sweep: thread owns whole 4x4 blocks; coalesced stores ----
    float* Xg = X + g * X_PER_G;
#pragma unroll
    for (int k = 0; k < 4; k++) {
        int b = k * 512 + tid;
        if (b < 1600) {
            int bi = b / 40;
            int bj = b - bi * 40;
            int ridx;
            if (bi == bj) {
                ridx = 780 + bi;
            } else {
                int mn = min(bi, bj), mx = max(bi, bj);
                ridx = 39 * mn - ((mn * (mn - 1)) >> 1) + (mx - mn - 1);
            }
            const float* ep = sEP + ridx * 10;
            float2 e0 = *(const float2*)(ep + 0);
            float2 e1 = *(const float2*)(ep + 2);
            float2 e2 = *(const float2*)(ep + 4);
            float2 e3 = *(const float2*)(ep + 6);
            float2 e4 = *(const float2*)(ep + 8);
            float f0 = e0.x, f1 = e0.y, f2 = e1.x, f3 = e1.y;
            float f4 = e2.x, f5 = e2.y, f6 = e3.x, f7 = e3.y;
            float f8 = e4.x, f9 = e4.y;
            float4 r0 = make_float4(f0, f1, f2, f3);
            float4 r1 = make_float4(f1, f4, f5, f6);
            float4 r2 = make_float4(f2, f5, f7, f8);
            float4 r3 = make_float4(f3, f6, f8, f9);
            float* p = Xg + (4 * bi) * X_STRIDE + 4 * bj;
            *(float4*)(p + 0 * X_STRIDE) = r0;
            *(float4*)(p + 1 * X_STRIDE) = r1;
            *(float4*)(p + 2 * X_STRIDE) = r2;
            *(float4*)(p + 3 * X_STRIDE) = r3;
        }
    }
}

// ---------------------------------------------------------------------------
// Launch
// ---------------------------------------------------------------------------
extern "C" void kernel_launch(void* const* d_in, const int* in_sizes, int n_in,
                              void* d_out, int out_size, void* d_ws, size_t ws_size,
                              hipStream_t stream) {
    const float* x   = (const float*)d_in[0];
    const float* Wg0 = (const float*)d_in[4];
    const float* bg0 = (const float*)d_in[5];
    const float* Wg1 = (const float*)d_in[6];
    const float* bg1 = (const float*)d_in[7];
    const float* Wg2 = (const float*)d_in[8];
    const float* bg2 = (const float*)d_in[9];
    const float* Wn0 = (const float*)d_in[10];
    const float* bn0 = (const float*)d_in[11];
    const float* Wn1 = (const float*)d_in[12];
    const float* bn1 = (const float*)d_in[13];
    const float* Wn2 = (const float*)d_in[14];
    const float* bn2 = (const float*)d_in[15];
    const float* We0 = (const float*)d_in[16];
    const float* be0 = (const float*)d_in[17];
    const float* We1 = (const float*)d_in[18];
    const float* be1 = (const float*)d_in[19];
    const float* We2 = (const float*)d_in[20];
    const float* be2 = (const float*)d_in[21];

    float* hout = (float*)d_out;            // h: 40960 x 64 fp32
    float* X    = hout + H_ELEMS;           // X: 1024 x 160 x 160 fp32
    unsigned short* wp = (unsigned short*)d_ws;  // 18432 bf16 packed weights

    k_prep<<<72, 256, 0, stream>>>(We0, We1, We2, Wn0, Wn1, Wn2, wp);
    k_fused<<<G_GRAPHS, 512, 0, stream>>>(x, Wg0, bg0, Wg1, bg1, Wg2, bg2,
                                          wp, be0, be1, be2, bn0, bn1, bn2,
                                          hout, X);
}

// Round 9
// 204.259 us; speedup vs baseline: 1.3686x; 1.0789x over previous
//
#include <hip/hip_runtime.h>

// Problem constants
#define G_GRAPHS 1024
#define N_NODES  40
#define M_EDGES  780          // N*(N-1)/2
#define NUM_NODES (G_GRAPHS * N_NODES)          // 40960
#define H_ELEMS  (NUM_NODES * 64)               // 2621440
#define X_STRIDE 160
#define X_PER_G  25600
#define SLOPE 0.1f

#define PACK_PER_MLP 9216     // W0(4096) + W1(4096) + W2(1024) bf16 elems

typedef __bf16 bf16x8 __attribute__((ext_vector_type(8)));
typedef unsigned short us8 __attribute__((ext_vector_type(8)));
typedef float f32x4 __attribute__((ext_vector_type(4)));

__device__ __forceinline__ float lrelu(float v) { return fmaxf(v, SLOPE * v); }
__device__ __forceinline__ unsigned short f2bf(float x) {
    __bf16 b = (__bf16)x;                       // RNE convert
    return __builtin_bit_cast(unsigned short, b);
}
__device__ __forceinline__ unsigned int pk2bf(float a, float b) {
    return (unsigned int)f2bf(a) | ((unsigned int)f2bf(b) << 16);
}

// ---------------------------------------------------------------------------
// K0: pack MLP weights (bf16) in d_ws. Layout serves the A-frag role:
// element for lane l, reg j, tile (mt,kt) of W^T is
// W[kt*32 + ((l>>4)&3)*8 + j][mt*16 + (l&15)]  -> linear ((mt*2+kt)*64+l)*8+j.
// W2 padded 10->16 cols (zeros). [0..9215] edge MLP, [9216..18431] node MLP.
// ---------------------------------------------------------------------------
__global__ __launch_bounds__(256) void k_prep(const float* __restrict__ We0,
                                              const float* __restrict__ We1,
                                              const float* __restrict__ We2,
                                              const float* __restrict__ Wn0,
                                              const float* __restrict__ Wn1,
                                              const float* __restrict__ Wn2,
                                              unsigned short* __restrict__ wp) {
    int t = blockIdx.x * 256 + threadIdx.x;     // 0..18431 (72 blocks)
    int mlp = t / PACK_PER_MLP;
    int o = t - mlp * PACK_PER_MLP;
    const float* W0 = mlp ? Wn0 : We0;
    const float* W1 = mlp ? Wn1 : We1;
    const float* W2 = mlp ? Wn2 : We2;
    float val;
    if (o < 8192) {
        const float* W = (o < 4096) ? W0 : W1;
        int idx = o & 4095;
        int j = idx & 7, l = (idx >> 3) & 63, tt = idx >> 9;   // tt = mt*2+kt
        int kt = tt & 1, mt = tt >> 1;
        int k = kt * 32 + ((l >> 4) & 3) * 8 + j;
        int m = mt * 16 + (l & 15);
        val = W[k * 64 + m];
    } else {
        int idx = o - 8192;                      // 0..1023, mt=0 only
        int j = idx & 7, l = (idx >> 3) & 63, kt = idx >> 9;
        int k = kt * 32 + ((l >> 4) & 3) * 8 + j;
        int m = l & 15;
        val = (m < 10) ? W2[k * 10 + m] : 0.f;
    }
    wp[mlp * PACK_PER_MLP + o] = f2bf(val);
}

// ---------------------------------------------------------------------------
// MLP machinery (verified round 6). Round-9: balanced chunk map — each wave
// runs 3 pairs (ILP-2) + at most 1 single; no dummy chunk 27; makespan 7
// chunks/wave vs round-6's 8. Memory path byte-identical to rounds 5/6
// (FETCH 1.8 MB / WRITE 112.6 MB measured ideal).
// ---------------------------------------------------------------------------
struct ChunkRegs {
    bf16x8 A1[4][2];
    bf16x8 A2[4][2];
    bf16x8 A3[2];
    float4 bv0[4];
    float4 bv1[4];
    float  bz[4];
};

__device__ __forceinline__ void run_pair(int R0A, int R0B, int w, int l,
                                         const float4* sh4,
                                         unsigned short* sBA,
                                         unsigned short* sBB,
                                         float* sEP,
                                         const unsigned short* sIJ,
                                         const ChunkRegs& cr) {
    const int nl = l & 15;
    const int rq = (l >> 4) & 3;
    const int rl = l >> 1;            // row within wave's 32-row slice
    const int hf2 = l & 1;            // feature half

    auto decode = [&](int row, int& ii, int& jj, bool& is_e, bool& is_n) {
        is_e = (row < 780);
        is_n = (row >= 800 && row < 840);
        ii = 0; jj = 0;
        if (is_e) {
            unsigned short e = sIJ[row];
            ii = e >> 8; jj = e & 255;
        } else if (is_n) {
            ii = jj = row - 800;
        }                              // else dummy row
    };
    int iiA, jjA, iiB, jjB; bool ieA, inA, ieB, inB;
    decode(R0A + rl, iiA, jjA, ieA, inA);
    decode(R0B + rl, iiB, jjB, ieB, inB);

    auto ebuild = [&](unsigned short* sB, int ii, int jj, bool is_e) {
        unsigned short tmp[32];
#pragma unroll
        for (int q = 0; q < 8; q++) {
            int u = hf2 * 8 + q;
            float4 a = sh4[ii * 16 + (u ^ ((ii & 7) << 1))];
            if (is_e) {
                float4 bq = sh4[jj * 16 + (u ^ ((jj & 7) << 1))];
                a.x += bq.x; a.y += bq.y; a.z += bq.z; a.w += bq.w;
            }
            tmp[4 * q + 0] = f2bf(a.x); tmp[4 * q + 1] = f2bf(a.y);
            tmp[4 * q + 2] = f2bf(a.z); tmp[4 * q + 3] = f2bf(a.w);
        }
        int r_sb = 32 * w + rl;
#pragma unroll
        for (int q = 0; q < 4; q++) {
            int cs = (hf2 * 4 + q) ^ (r_sb & 7);
            *(us8*)((char*)sB + r_sb * 128 + cs * 16) = *(const us8*)(tmp + 8 * q);
        }
    };
    ebuild(sBA, iiA, jjA, ieA);
    ebuild(sBB, iiB, jjB, ieB);

    auto ZB = [&](const unsigned short* s, int nt, int kt) -> bf16x8 {
        int node = 32 * w + nt * 16 + nl;
        int cs = (kt * 4 + rq) ^ (node & 7);
        return __builtin_bit_cast(bf16x8,
            *(const us8*)((const char*)s + node * 128 + cs * 16));
    };
    auto zstore = [&](unsigned short* s, int mt, int nt, const f32x4& v) {
        int node = 32 * w + nt * 16 + nl;
        int cs = (mt * 2 + (rq >> 1)) ^ (node & 7);
        uint2 u = make_uint2(pk2bf(v[0], v[1]), pk2bf(v[2], v[3]));
        *(uint2*)((char*)s + node * 128 + cs * 16 + (rq & 1) * 8) = u;
    };

    auto gemm_layer = [&](unsigned short* s, const bf16x8 A[4][2],
                          const float4* bv) {
        bf16x8 B[2][2];
#pragma unroll
        for (int nt = 0; nt < 2; nt++)
#pragma unroll
            for (int kt = 0; kt < 2; kt++) B[nt][kt] = ZB(s, nt, kt);
#pragma unroll
        for (int mt = 0; mt < 4; mt++) {
            float4 b = bv[mt];
#pragma unroll
            for (int nt = 0; nt < 2; nt++) {
                f32x4 acc = (f32x4){b.x, b.y, b.z, b.w};   // bias as C-input
                acc = __builtin_amdgcn_mfma_f32_16x16x32_bf16(A[mt][0], B[nt][0], acc, 0, 0, 0);
                acc = __builtin_amdgcn_mfma_f32_16x16x32_bf16(A[mt][1], B[nt][1], acc, 0, 0, 0);
                f32x4 z;
                z[0] = lrelu(acc[0]); z[1] = lrelu(acc[1]);
                z[2] = lrelu(acc[2]); z[3] = lrelu(acc[3]);
                zstore(s, mt, nt, z);
            }
        }
    };

    gemm_layer(sBA, cr.A1, cr.bv0);
    gemm_layer(sBB, cr.A1, cr.bv0);
    gemm_layer(sBA, cr.A2, cr.bv1);
    gemm_layer(sBB, cr.A2, cr.bv1);

    auto gemm3 = [&](unsigned short* s, int R0) {
        bf16x8 B[2][2];
#pragma unroll
        for (int nt = 0; nt < 2; nt++)
#pragma unroll
            for (int kt = 0; kt < 2; kt++) B[nt][kt] = ZB(s, nt, kt);
#pragma unroll
        for (int nt = 0; nt < 2; nt++) {
            f32x4 acc = (f32x4){cr.bz[0], cr.bz[1], cr.bz[2], cr.bz[3]};
            acc = __builtin_amdgcn_mfma_f32_16x16x32_bf16(cr.A3[0], B[nt][0], acc, 0, 0, 0);
            acc = __builtin_amdgcn_mfma_f32_16x16x32_bf16(cr.A3[1], B[nt][1], acc, 0, 0, 0);
            int rowe = R0 + nt * 16 + nl;
            bool valid = (rowe < 780) || (rowe >= 800 && rowe < 840);
            if (valid && rq < 3) {
                int epr = (rowe < 780) ? rowe : rowe - 20;   // nodes -> 780..819
                float* p = sEP + epr * 10 + rq * 4;
                *(float2*)p = make_float2(acc[0], acc[1]);
                if (rq < 2)
                    *(float2*)(p + 2) = make_float2(acc[2], acc[3]);
            }
        }
    };
    gemm3(sBA, R0A);
    gemm3(sBB, R0B);
}

// single-chain chunk (uses the wave's sBA slice only)
__device__ __forceinline__ void run_single(int R0, int w, int l,
                                           const float4* sh4,
                                           unsigned short* sBA,
                                           float* sEP,
                                           const unsigned short* sIJ,
                                           const ChunkRegs& cr) {
    const int nl = l & 15;
    const int rq = (l >> 4) & 3;
    const int rl = l >> 1;
    const int hf2 = l & 1;
    const int row = R0 + rl;

    const bool is_e = (row < 780);
    const bool is_n = (row >= 800 && row < 840);
    int ii = 0, jj = 0;
    if (is_e) {
        unsigned short e = sIJ[row];
        ii = e >> 8; jj = e & 255;
    } else if (is_n) {
        ii = jj = row - 800;
    }

    {
        unsigned short tmp[32];
#pragma unroll
        for (int q = 0; q < 8; q++) {
            int u = hf2 * 8 + q;
            float4 a = sh4[ii * 16 + (u ^ ((ii & 7) << 1))];
            if (is_e) {
                float4 bq = sh4[jj * 16 + (u ^ ((jj & 7) << 1))];
                a.x += bq.x; a.y += bq.y; a.z += bq.z; a.w += bq.w;
            }
            tmp[4 * q + 0] = f2bf(a.x); tmp[4 * q + 1] = f2bf(a.y);
            tmp[4 * q + 2] = f2bf(a.z); tmp[4 * q + 3] = f2bf(a.w);
        }
        int r_sb = 32 * w + rl;
#pragma unroll
        for (int q = 0; q < 4; q++) {
            int cs = (hf2 * 4 + q) ^ (r_sb & 7);
            *(us8*)((char*)sBA + r_sb * 128 + cs * 16) = *(const us8*)(tmp + 8 * q);
        }
    }

    auto ZB = [&](int nt, int kt) -> bf16x8 {
        int node = 32 * w + nt * 16 + nl;
        int cs = (kt * 4 + rq) ^ (node & 7);
        return __builtin_bit_cast(bf16x8,
            *(const us8*)((const char*)sBA + node * 128 + cs * 16));
    };
    auto zstore = [&](int mt, int nt, const f32x4& v) {
        int node = 32 * w + nt * 16 + nl;
        int cs = (mt * 2 + (rq >> 1)) ^ (node & 7);
        uint2 u = make_uint2(pk2bf(v[0], v[1]), pk2bf(v[2], v[3]));
        *(uint2*)((char*)sBA + node * 128 + cs * 16 + (rq & 1) * 8) = u;
    };
    auto gemm_layer = [&](const bf16x8 A[4][2], const float4* bv) {
        bf16x8 B[2][2];
#pragma unroll
        for (int nt = 0; nt < 2; nt++)
#pragma unroll
            for (int kt = 0; kt < 2; kt++) B[nt][kt] = ZB(nt, kt);
#pragma unroll
        for (int mt = 0; mt < 4; mt++) {
            float4 b = bv[mt];
#pragma unroll
            for (int nt = 0; nt < 2; nt++) {
                f32x4 acc = (f32x4){b.x, b.y, b.z, b.w};
                acc = __builtin_amdgcn_mfma_f32_16x16x32_bf16(A[mt][0], B[nt][0], acc, 0, 0, 0);
                acc = __builtin_amdgcn_mfma_f32_16x16x32_bf16(A[mt][1], B[nt][1], acc, 0, 0, 0);
                f32x4 z;
                z[0] = lrelu(acc[0]); z[1] = lrelu(acc[1]);
                z[2] = lrelu(acc[2]); z[3] = lrelu(acc[3]);
                zstore(mt, nt, z);
            }
        }
    };
    gemm_layer(cr.A1, cr.bv0);
    gemm_layer(cr.A2, cr.bv1);
    {
        bf16x8 B[2][2];
#pragma unroll
        for (int nt = 0; nt < 2; nt++)
#pragma unroll
            for (int kt = 0; kt < 2; kt++) B[nt][kt] = ZB(nt, kt);
#pragma unroll
        for (int nt = 0; nt < 2; nt++) {
            f32x4 acc = (f32x4){cr.bz[0], cr.bz[1], cr.bz[2], cr.bz[3]};
            acc = __builtin_amdgcn_mfma_f32_16x16x32_bf16(cr.A3[0], B[nt][0], acc, 0, 0, 0);
            acc = __builtin_amdgcn_mfma_f32_16x16x32_bf16(cr.A3[1], B[nt][1], acc, 0, 0, 0);
            int rowe = R0 + nt * 16 + nl;
            bool valid = (rowe < 780) || (rowe >= 800 && rowe < 840);
            if (valid && rq < 3) {
                int epr = (rowe < 780) ? rowe : rowe - 20;
                float* p = sEP + epr * 10 + rq * 4;
                *(float2*)p = make_float2(acc[0], acc[1]);
                if (rq < 2)
                    *(float2*)(p + 2) = make_float2(acc[2], acc[3]);
            }
        }
    }
}

// ---------------------------------------------------------------------------
// K1 (fused): GCN + pair-ILP MLP + coalesced X sweep, one graph per block.
// LDS arena (77,368 B, 2 blocks/CU — LDS-limited; VGPR has headroom):
//   [0,     10240)  sh   : final h, 40x64 f32, swizzled | GCN: h0@0
//   [10240, 26624)  sBA  : chain-A GEMM ping            | GCN: h1@20480
//   [26624, 43008)  sBB  : chain-B GEMM ping            | GCN: h2@26624
//   [43008, 75808)  sEP  : 820x10 f32 MLP outputs       | GCN: P@43008
//   [75808, 77368)  sIJ  : edge (i<<8|j) decode table
// Round-9 GCN: register-colsum — each thread accumulates the colsum partial
// of the rows IT computes during the matmul (no buf LDS array at all),
// writes P once, reads P after one barrier, and recomputes h_next from the
// register copies. 10 barriers -> 7; write/read positions identical to
// round 6 (same tid decomposition) so numerics are bit-identical.
// ---------------------------------------------------------------------------
__global__ __launch_bounds__(256, 2) void k_fused(const float* __restrict__ x,
                                                  const float* __restrict__ Wg0,
                                                  const float* __restrict__ bg0,
                                                  const float* __restrict__ Wg1,
                                                  const float* __restrict__ bg1,
                                                  const float* __restrict__ Wg2,
                                                  const float* __restrict__ bg2,
                                                  const unsigned short* __restrict__ wp,
                                                  const float* __restrict__ be0,
                                                  const float* __restrict__ be1,
                                                  const float* __restrict__ be2,
                                                  const float* __restrict__ bn0,
                                                  const float* __restrict__ bn1,
                                                  const float* __restrict__ bn2,
                                                  float* __restrict__ hout,
                                                  float* __restrict__ X) {
    __shared__ __align__(16) char smem[77368];
    float* sh           = (float*)smem;                      // [0,10240)
    unsigned short* sBA = (unsigned short*)(smem + 10240);   // [10240,26624)
    unsigned short* sBB = (unsigned short*)(smem + 26624);   // [26624,43008)
    float* sEP          = (float*)(smem + 43008);            // [43008,75808)
    unsigned short* sIJ = (unsigned short*)(smem + 75808);   // [75808,77368)
    // GCN-phase aliases
    float* h0  = (float*)smem;                               // [0,960)
    float* h1  = (float*)(smem + 20480);                     // [20480,25600)
    float* h2  = (float*)(smem + 26624);                     // [26624,31744)
    float* P   = (float*)(smem + 43008);                     // [43008,45056)

    const int g = blockIdx.x;
    const int tid = threadIdx.x;
    const int l = tid & 63;
    const int w = tid >> 6;
    const float inv39 = 1.0f / 39.0f;
    const int c32 = tid & 31;
    const int c64 = tid & 63;
    const int rq = (l >> 4) & 3;

    // ---- build edge decode table (once per block; covered by bar #1) ----
    for (int m = tid; m < 780; m += 256) {
        float tq = 6241.0f - 8.0f * (float)m;      // exact in fp32
        int i0 = (int)(0.5f * (79.0f - sqrtf(tq)));
        i0 = min(38, max(0, i0));
        int cum = 39 * i0 - ((i0 * (i0 - 1)) >> 1);
        if (cum > m) { --i0; cum = 39 * i0 - ((i0 * (i0 - 1)) >> 1); }
        else if (m - cum >= 39 - i0) { cum += 39 - i0; ++i0; }
        int jj = i0 + 1 + (m - cum);
        sIJ[m] = (unsigned short)((i0 << 8) | jj);
    }

    // =========================== GCN phase ===========================
    {
        float w0c[6], w1c[32], w2c[32];
#pragma unroll
        for (int f = 0; f < 6; f++)  w0c[f] = Wg0[f * 32 + c32];
#pragma unroll
        for (int m = 0; m < 32; m++) w1c[m] = Wg1[m * 32 + c32];
#pragma unroll
        for (int m = 0; m < 32; m++) w2c[m] = Wg2[m * 64 + c64];
        const float b0c = bg0[c32];
        const float b1c = bg1[c32];
        const float b2c = bg2[c64];

        if (tid < 240) {
            int n = tid / 6, f = tid - n * 6;
            h0[tid] = x[(g * N_NODES + n) * 16 + f];
        }
        __syncthreads();                                      // bar 1

        float breg[10];
        const int n0 = tid >> 5;        // 0..7 (layers 0/1)

        // ---- layer 0: regs = h0 @ Wg0 col c32; P = colsum partial ----
        {
            float psum = 0.f;
#pragma unroll
            for (int t = 0; t < 5; t++) {
                int n = n0 + 8 * t;
                float s = 0.f;
#pragma unroll
                for (int f = 0; f < 6; f++) s += h0[n * 6 + f] * w0c[f];
                breg[t] = s; psum += s;
            }
            P[n0 * 32 + c32] = psum;
        }
        __syncthreads();                                      // bar 2
        {
            float s0 = 0.f;
#pragma unroll
            for (int grp = 0; grp < 8; grp++) s0 += P[grp * 32 + c32];
#pragma unroll
            for (int t = 0; t < 5; t++)
                h1[(n0 + 8 * t) * 32 + c32] = lrelu((s0 - breg[t]) * inv39 + b0c);
        }
        __syncthreads();                                      // bar 3

        // ---- layer 1 ----
        {
            float psum = 0.f;
#pragma unroll
            for (int t = 0; t < 5; t++) {
                int n = n0 + 8 * t;
                const float4* hp = (const float4*)(h1 + n * 32);
                float s = 0.f;
#pragma unroll
                for (int q = 0; q < 8; q++) {
                    float4 hv = hp[q];
                    s += hv.x * w1c[4 * q + 0] + hv.y * w1c[4 * q + 1]
                       + hv.z * w1c[4 * q + 2] + hv.w * w1c[4 * q + 3];
                }
                breg[t] = s; psum += s;
            }
            P[n0 * 32 + c32] = psum;
        }
        __syncthreads();                                      // bar 4
        {
            float s0 = 0.f;
#pragma unroll
            for (int grp = 0; grp < 8; grp++) s0 += P[grp * 32 + c32];
#pragma unroll
            for (int t = 0; t < 5; t++)
                h2[(n0 + 8 * t) * 32 + c32] = lrelu((s0 - breg[t]) * inv39 + b1c);
        }
        __syncthreads();                                      // bar 5

        // ---- layer 2 (64-wide; 10 rows/thread) ----
        const int n02 = tid >> 6;       // 0..3
        {
            float psum = 0.f;
#pragma unroll
            for (int t = 0; t < 10; t++) {
                int n = n02 + 4 * t;
                const float4* hp = (const float4*)(h2 + n * 32);
                float s = 0.f;
#pragma unroll
                for (int q = 0; q < 8; q++) {
                    float4 hv = hp[q];
                    s += hv.x * w2c[4 * q + 0] + hv.y * w2c[4 * q + 1]
                       + hv.z * w2c[4 * q + 2] + hv.w * w2c[4 * q + 3];
                }
                breg[t] = s; psum += s;
            }
            P[n02 * 64 + c64] = psum;
        }
        __syncthreads();                                      // bar 6
        // ---- epilogue: write hout (global) + sh (LDS, swizzled) ----
        {
            float s0 = 0.f;
#pragma unroll
            for (int grp = 0; grp < 4; grp++) s0 += P[grp * 64 + c64];
#pragma unroll
            for (int t = 0; t < 10; t++) {
                int n = n02 + 4 * t;
                float v = (s0 - breg[t]) * inv39 + b2c;
                hout[g * N_NODES * 64 + n * 64 + c64] = v;
                int u = c64 >> 2;
                int us = u ^ ((n & 7) << 1);
                sh[n * 64 + us * 4 + (c64 & 3)] = v;
            }
        }
    }
    __syncthreads();   // bar 7: sh + sIJ ready; GCN scratch dead

    // =========================== MLP phase ===========================
    const float4* sh4 = (const float4*)sh;

    auto WA = [&](const unsigned short* base, int mt, int kt) -> bf16x8 {
        return __builtin_bit_cast(bf16x8,
            *(const us8*)(base + ((mt * 2 + kt) * 64 + l) * 8));
    };
    auto loadW = [&](ChunkRegs& cr, const unsigned short* wb,
                     const float* B0, const float* B1, const float* B2) {
#pragma unroll
        for (int mt = 0; mt < 4; mt++) {
#pragma unroll
            for (int kt = 0; kt < 2; kt++) {
                cr.A1[mt][kt] = WA(wb, mt, kt);
                cr.A2[mt][kt] = WA(wb + 4096, mt, kt);
            }
            cr.bv0[mt] = *(const float4*)(B0 + mt * 16 + rq * 4);
            cr.bv1[mt] = *(const float4*)(B1 + mt * 16 + rq * 4);
        }
        cr.A3[0] = WA(wb + 8192, 0, 0);
        cr.A3[1] = WA(wb + 8192, 0, 1);
#pragma unroll
        for (int k = 0; k < 4; k++) {
            int f = rq * 4 + k;
            cr.bz[k] = (f < 10) ? B2[f] : 0.f;
        }
    };

    ChunkRegs ce;
    loadW(ce, wp, be0, be1, be2);            // edge MLP weights

    // balanced chunk map (27 real chunks, no dummy chunk):
    //   wave 0: pairs (0,1)(8,9)(16,17)   + single 24 (edge)
    //   wave 1: pairs (2,3)(10,11)(18,19) + single 25 (node)
    //   wave 2: pairs (4,5)(12,13)(20,21) + single 26 (node)
    //   wave 3: pairs (6,7)(14,15)(22,23)
    // node loadW-overwrite is each wave's LAST iteration (pairs all edge).
#pragma unroll
    for (int t = 0; t < 3; t++) {
        int c1 = 2 * w + 8 * t;
        run_pair(32 * c1, 32 * (c1 + 1), w, l, sh4, sBA, sBB, sEP, sIJ, ce);
    }
    if (w == 0) {
        run_single(32 * 24, w, l, sh4, sBA, sEP, sIJ, ce);
    } else if (w == 1) {
        loadW(ce, wp + PACK_PER_MLP, bn0, bn1, bn2);
        run_single(32 * 25, w, l, sh4, sBA, sEP, sIJ, ce);
    } else if (w == 2) {
        loadW(ce, wp + PACK_PER_MLP, bn0, bn1, bn2);
        run_single(32 * 26, w, l, sh4, sBA, sEP, sIJ, ce);
    }

    __syncthreads();   // all EP rows ready

    // ---- X sweep: thread owns whole 4x4 blocks; coalesced stores ----
    float* Xg = X + g * X_PER_G;
#pragma unroll
    for (int k = 0; k < 7; k++) {
        int b = k * 256 + tid;
        if (b < 1600) {
            int bi = b / 40;
            int bj = b - bi * 40;
            int ridx;
            if (bi == bj) {
                ridx = 780 + bi;
            } else {
                int mn = min(bi, bj), mx = max(bi, bj);
                ridx = 39 * mn - ((mn * (mn - 1)) >> 1) + (mx - mn - 1);
            }
            const float* ep = sEP + ridx * 10;
            float2 e0 = *(const float2*)(ep + 0);
            float2 e1 = *(const float2*)(ep + 2);
            float2 e2 = *(const float2*)(ep + 4);
            float2 e3 = *(const float2*)(ep + 6);
            float2 e4 = *(const float2*)(ep + 8);
            float f0 = e0.x, f1 = e0.y, f2 = e1.x, f3 = e1.y;
            float f4 = e2.x, f5 = e2.y, f6 = e3.x, f7 = e3.y;
            float f8 = e4.x, f9 = e4.y;
            float4 r0 = make_float4(f0, f1, f2, f3);
            float4 r1 = make_float4(f1, f4, f5, f6);
            float4 r2 = make_float4(f2, f5, f7, f8);
            float4 r3 = make_float4(f3, f6, f8, f9);
            float* p = Xg + (4 * bi) * X_STRIDE + 4 * bj;
            *(float4*)(p + 0 * X_STRIDE) = r0;
            *(float4*)(p + 1 * X_STRIDE) = r1;
            *(float4*)(p + 2 * X_STRIDE) = r2;
            *(float4*)(p + 3 * X_STRIDE) = r3;
        }
    }
}

// ---------------------------------------------------------------------------
// Launch
// ---------------------------------------------------------------------------
extern "C" void kernel_launch(void* const* d_in, const int* in_sizes, int n_in,
                              void* d_out, int out_size, void* d_ws, size_t ws_size,
                              hipStream_t stream) {
    const float* x   = (const float*)d_in[0];
    const float* Wg0 = (const float*)d_in[4];
    const float* bg0 = (const float*)d_in[5];
    const float* Wg1 = (const float*)d_in[6];
    const float* bg1 = (const float*)d_in[7];
    const float* Wg2 = (const float*)d_in[8];
    const float* bg2 = (const float*)d_in[9];
    const float* Wn0 = (const float*)d_in[10];
    const float* bn0 = (const float*)d_in[11];
    const float* Wn1 = (const float*)d_in[12];
    const float* bn1 = (const float*)d_in[13];
    const float* Wn2 = (const float*)d_in[14];
    const float* bn2 = (const float*)d_in[15];
    const float* We0 = (const float*)d_in[16];
    const float* be0 = (const float*)d_in[17];
    const float* We1 = (const float*)d_in[18];
    const float* be1 = (const float*)d_in[19];
    const float* We2 = (const float*)d_in[20];
    const float* be2 = (const float*)d_in[21];

    float* hout = (float*)d_out;            // h: 40960 x 64 fp32
    float* X    = hout + H_ELEMS;           // X: 1024 x 160 x 160 fp32
    unsigned short* wp = (unsigned short*)d_ws;  // 18432 bf16 packed weights

    k_prep<<<72, 256, 0, stream>>>(We0, We1, We2, Wn0, Wn1, Wn2, wp);
    k_fused<<<G_GRAPHS, 256, 0, stream>>>(x, Wg0, bg0, Wg1, bg1, Wg2, bg2,
                                          wp, be0, be1, be2, bn0, bn1, bn2,
                                          hout, X);
}

// Round 10
// 202.357 us; speedup vs baseline: 1.3815x; 1.0094x over previous
//
#include <hip/hip_runtime.h>

// Problem constants
#define G_GRAPHS 1024
#define N_NODES  40
#define M_EDGES  780          // N*(N-1)/2
#define NUM_NODES (G_GRAPHS * N_NODES)          // 40960
#define H_ELEMS  (NUM_NODES * 64)               // 2621440
#define X_STRIDE 160
#define X_PER_G  25600
#define SLOPE 0.1f

#define PACK_PER_MLP 9216     // W0(4096) + W1(4096) + W2(1024) bf16 elems

typedef __bf16 bf16x8 __attribute__((ext_vector_type(8)));
typedef unsigned short us8 __attribute__((ext_vector_type(8)));
typedef float f32x4 __attribute__((ext_vector_type(4)));

__device__ __forceinline__ float lrelu(float v) { return fmaxf(v, SLOPE * v); }
__device__ __forceinline__ unsigned short f2bf(float x) {
    __bf16 b = (__bf16)x;                       // RNE convert
    return __builtin_bit_cast(unsigned short, b);
}
__device__ __forceinline__ unsigned int pk2bf(float a, float b) {
    return (unsigned int)f2bf(a) | ((unsigned int)f2bf(b) << 16);
}

// ---------------------------------------------------------------------------
// K0: pack MLP weights (bf16) in d_ws. Layout serves the A-frag role:
// element for lane l, reg j, tile (mt,kt) of W^T is
// W[kt*32 + ((l>>4)&3)*8 + j][mt*16 + (l&15)]  -> linear ((mt*2+kt)*64+l)*8+j.
// W2 padded 10->16 cols (zeros). [0..9215] edge MLP, [9216..18431] node MLP.
// ---------------------------------------------------------------------------
__global__ __launch_bounds__(256) void k_prep(const float* __restrict__ We0,
                                              const float* __restrict__ We1,
                                              const float* __restrict__ We2,
                                              const float* __restrict__ Wn0,
                                              const float* __restrict__ Wn1,
                                              const float* __restrict__ Wn2,
                                              unsigned short* __restrict__ wp) {
    int t = blockIdx.x * 256 + threadIdx.x;     // 0..18431 (72 blocks)
    int mlp = t / PACK_PER_MLP;
    int o = t - mlp * PACK_PER_MLP;
    const float* W0 = mlp ? Wn0 : We0;
    const float* W1 = mlp ? Wn1 : We1;
    const float* W2 = mlp ? Wn2 : We2;
    float val;
    if (o < 8192) {
        const float* W = (o < 4096) ? W0 : W1;
        int idx = o & 4095;
        int j = idx & 7, l = (idx >> 3) & 63, tt = idx >> 9;   // tt = mt*2+kt
        int kt = tt & 1, mt = tt >> 1;
        int k = kt * 32 + ((l >> 4) & 3) * 8 + j;
        int m = mt * 16 + (l & 15);
        val = W[k * 64 + m];
    } else {
        int idx = o - 8192;                      // 0..1023, mt=0 only
        int j = idx & 7, l = (idx >> 3) & 63, kt = idx >> 9;
        int k = kt * 32 + ((l >> 4) & 3) * 8 + j;
        int m = l & 15;
        val = (m < 10) ? W2[k * 10 + m] : 0.f;
    }
    wp[mlp * PACK_PER_MLP + o] = f2bf(val);
}

// ---------------------------------------------------------------------------
// MLP machinery. Round-10: E-build replaced by MFMA gather (GEMM0, E = S.h):
// per chunk, each lane-pair ZEROES its S row (4 ds_write_b128, same addressing
// as the old ebuild stores) + scatters 1.0bf16 at k=i (hf2=0) / k=j (hf2=1);
// 16 MFMAs with h pre-packed in the A-frag layout (registers) produce E in
// C/D layout -> zstore_raw. Deletes 16 sh-reads + 8 f32x4 adds + 32 bf16
// converts per thread per chunk AND the sh-read latency chain; work moves to
// the 90%-idle MFMA pipe. Memory path byte-identical to rounds 5-9.
// ---------------------------------------------------------------------------
struct ChunkRegs {
    bf16x8 A1[4][2];
    bf16x8 A2[4][2];
    bf16x8 A3[2];
    float4 bv0[4];
    float4 bv1[4];
    float  bz[4];
};

__device__ __forceinline__ void run_pair(int R0A, int R0B, int w, int l,
                                         const bf16x8 (&hAf)[4][2],
                                         unsigned short* sBA,
                                         unsigned short* sBB,
                                         float* sEP,
                                         const unsigned short* sIJ,
                                         const ChunkRegs& cr) {
    const int nl = l & 15;
    const int rq = (l >> 4) & 3;
    const int rl = l >> 1;            // row within wave's 32-row slice
    const int hf2 = l & 1;            // row-half role
    const int r_sb = 32 * w + rl;

    auto decode = [&](int row, int& ii, int& jj, bool& is_e, bool& is_n) {
        is_e = (row < 780);
        is_n = (row >= 800 && row < 840);
        ii = 0; jj = 0;
        if (is_e) {
            unsigned short e = sIJ[row];
            ii = e >> 8; jj = e & 255;
        } else if (is_n) {
            ii = jj = row - 800;
        }                              // else dummy row
    };
    int iiA, jjA, iiB, jjB; bool ieA, inA, ieB, inB;
    decode(R0A + rl, iiA, jjA, ieA, inA);
    decode(R0B + rl, iiB, jjB, ieB, inB);

    // ---- S build: zero both rows, scatter ones (same wave -> in order) ----
    {
        us8 z = {};
#pragma unroll
        for (int q = 0; q < 4; q++) {
            int cs = (hf2 * 4 + q) ^ (r_sb & 7);
            *(us8*)((char*)sBA + r_sb * 128 + cs * 16) = z;
            *(us8*)((char*)sBB + r_sb * 128 + cs * 16) = z;
        }
        int kA = hf2 ? jjA : iiA;
        bool wA = hf2 ? ieA : (ieA || inA);
        if (wA) {
            int cs = (kA >> 3) ^ (r_sb & 7);
            *(unsigned short*)((char*)sBA + r_sb * 128 + cs * 16 + (kA & 7) * 2) = 0x3F80;
        }
        int kB = hf2 ? jjB : iiB;
        bool wB = hf2 ? ieB : (ieB || inB);
        if (wB) {
            int cs = (kB >> 3) ^ (r_sb & 7);
            *(unsigned short*)((char*)sBB + r_sb * 128 + cs * 16 + (kB & 7) * 2) = 0x3F80;
        }
    }

    auto ZB = [&](const unsigned short* s, int nt, int kt) -> bf16x8 {
        int node = 32 * w + nt * 16 + nl;
        int cs = (kt * 4 + rq) ^ (node & 7);
        return __builtin_bit_cast(bf16x8,
            *(const us8*)((const char*)s + node * 128 + cs * 16));
    };
    auto zstore_raw = [&](unsigned short* s, int mt, int nt, const f32x4& v) {
        int node = 32 * w + nt * 16 + nl;
        int cs = (mt * 2 + (rq >> 1)) ^ (node & 7);
        uint2 u = make_uint2(pk2bf(v[0], v[1]), pk2bf(v[2], v[3]));
        *(uint2*)((char*)s + node * 128 + cs * 16 + (rq & 1) * 8) = u;
    };
    auto zstore = [&](unsigned short* s, int mt, int nt, const f32x4& v) {
        f32x4 z;
        z[0] = lrelu(v[0]); z[1] = lrelu(v[1]);
        z[2] = lrelu(v[2]); z[3] = lrelu(v[3]);
        zstore_raw(s, mt, nt, z);
    };

    // ---- GEMM0: E = hA . S -> in place over S ----
    auto gemm0 = [&](unsigned short* s) {
        bf16x8 B[2][2];
#pragma unroll
        for (int nt = 0; nt < 2; nt++)
#pragma unroll
            for (int kt = 0; kt < 2; kt++) B[nt][kt] = ZB(s, nt, kt);
#pragma unroll
        for (int mt = 0; mt < 4; mt++)
#pragma unroll
            for (int nt = 0; nt < 2; nt++) {
                f32x4 acc = (f32x4){0.f, 0.f, 0.f, 0.f};
                acc = __builtin_amdgcn_mfma_f32_16x16x32_bf16(hAf[mt][0], B[nt][0], acc, 0, 0, 0);
                acc = __builtin_amdgcn_mfma_f32_16x16x32_bf16(hAf[mt][1], B[nt][1], acc, 0, 0, 0);
                zstore_raw(s, mt, nt, acc);
            }
    };
    gemm0(sBA);
    gemm0(sBB);

    auto gemm_layer = [&](unsigned short* s, const bf16x8 A[4][2],
                          const float4* bv) {
        bf16x8 B[2][2];
#pragma unroll
        for (int nt = 0; nt < 2; nt++)
#pragma unroll
            for (int kt = 0; kt < 2; kt++) B[nt][kt] = ZB(s, nt, kt);
#pragma unroll
        for (int mt = 0; mt < 4; mt++) {
            float4 b = bv[mt];
#pragma unroll
            for (int nt = 0; nt < 2; nt++) {
                f32x4 acc = (f32x4){b.x, b.y, b.z, b.w};   // bias as C-input
                acc = __builtin_amdgcn_mfma_f32_16x16x32_bf16(A[mt][0], B[nt][0], acc, 0, 0, 0);
                acc = __builtin_amdgcn_mfma_f32_16x16x32_bf16(A[mt][1], B[nt][1], acc, 0, 0, 0);
                zstore(s, mt, nt, acc);
            }
        }
    };

    gemm_layer(sBA, cr.A1, cr.bv0);
    gemm_layer(sBB, cr.A1, cr.bv0);
    gemm_layer(sBA, cr.A2, cr.bv1);
    gemm_layer(sBB, cr.A2, cr.bv1);

    auto gemm3 = [&](unsigned short* s, int R0) {
        bf16x8 B[2][2];
#pragma unroll
        for (int nt = 0; nt < 2; nt++)
#pragma unroll
            for (int kt = 0; kt < 2; kt++) B[nt][kt] = ZB(s, nt, kt);
#pragma unroll
        for (int nt = 0; nt < 2; nt++) {
            f32x4 acc = (f32x4){cr.bz[0], cr.bz[1], cr.bz[2], cr.bz[3]};
            acc = __builtin_amdgcn_mfma_f32_16x16x32_bf16(cr.A3[0], B[nt][0], acc, 0, 0, 0);
            acc = __builtin_amdgcn_mfma_f32_16x16x32_bf16(cr.A3[1], B[nt][1], acc, 0, 0, 0);
            int rowe = R0 + nt * 16 + nl;
            bool valid = (rowe < 780) || (rowe >= 800 && rowe < 840);
            if (valid && rq < 3) {
                int epr = (rowe < 780) ? rowe : rowe - 20;   // nodes -> 780..819
                float* p = sEP + epr * 10 + rq * 4;
                *(float2*)p = make_float2(acc[0], acc[1]);
                if (rq < 2)
                    *(float2*)(p + 2) = make_float2(acc[2], acc[3]);
            }
        }
    };
    gemm3(sBA, R0A);
    gemm3(sBB, R0B);
}

// single-chain chunk (uses the wave's sBA slice only)
__device__ __forceinline__ void run_single(int R0, int w, int l,
                                           const bf16x8 (&hAf)[4][2],
                                           unsigned short* sBA,
                                           float* sEP,
                                           const unsigned short* sIJ,
                                           const ChunkRegs& cr) {
    const int nl = l & 15;
    const int rq = (l >> 4) & 3;
    const int rl = l >> 1;
    const int hf2 = l & 1;
    const int r_sb = 32 * w + rl;
    const int row = R0 + rl;

    const bool is_e = (row < 780);
    const bool is_n = (row >= 800 && row < 840);
    int ii = 0, jj = 0;
    if (is_e) {
        unsigned short e = sIJ[row];
        ii = e >> 8; jj = e & 255;
    } else if (is_n) {
        ii = jj = row - 800;
    }

    {
        us8 z = {};
#pragma unroll
        for (int q = 0; q < 4; q++) {
            int cs = (hf2 * 4 + q) ^ (r_sb & 7);
            *(us8*)((char*)sBA + r_sb * 128 + cs * 16) = z;
        }
        int kk = hf2 ? jj : ii;
        bool wr = hf2 ? is_e : (is_e || is_n);
        if (wr) {
            int cs = (kk >> 3) ^ (r_sb & 7);
            *(unsigned short*)((char*)sBA + r_sb * 128 + cs * 16 + (kk & 7) * 2) = 0x3F80;
        }
    }

    auto ZB = [&](int nt, int kt) -> bf16x8 {
        int node = 32 * w + nt * 16 + nl;
        int cs = (kt * 4 + rq) ^ (node & 7);
        return __builtin_bit_cast(bf16x8,
            *(const us8*)((const char*)sBA + node * 128 + cs * 16));
    };
    auto zstore_raw = [&](int mt, int nt, const f32x4& v) {
        int node = 32 * w + nt * 16 + nl;
        int cs = (mt * 2 + (rq >> 1)) ^ (node & 7);
        uint2 u = make_uint2(pk2bf(v[0], v[1]), pk2bf(v[2], v[3]));
        *(uint2*)((char*)sBA + node * 128 + cs * 16 + (rq & 1) * 8) = u;
    };

    // GEMM0
    {
        bf16x8 B[2][2];
#pragma unroll
        for (int nt = 0; nt < 2; nt++)
#pragma unroll
            for (int kt = 0; kt < 2; kt++) B[nt][kt] = ZB(nt, kt);
#pragma unroll
        for (int mt = 0; mt < 4; mt++)
#pragma unroll
            for (int nt = 0; nt < 2; nt++) {
                f32x4 acc = (f32x4){0.f, 0.f, 0.f, 0.f};
                acc = __builtin_amdgcn_mfma_f32_16x16x32_bf16(hAf[mt][0], B[nt][0], acc, 0, 0, 0);
                acc = __builtin_amdgcn_mfma_f32_16x16x32_bf16(hAf[mt][1], B[nt][1], acc, 0, 0, 0);
                zstore_raw(mt, nt, acc);
            }
    }

    auto gemm_layer = [&](const bf16x8 A[4][2], const float4* bv) {
        bf16x8 B[2][2];
#pragma unroll
        for (int nt = 0; nt < 2; nt++)
#pragma unroll
            for (int kt = 0; kt < 2; kt++) B[nt][kt] = ZB(nt, kt);
#pragma unroll
        for (int mt = 0; mt < 4; mt++) {
            float4 b = bv[mt];
#pragma unroll
            for (int nt = 0; nt < 2; nt++) {
                f32x4 acc = (f32x4){b.x, b.y, b.z, b.w};
                acc = __builtin_amdgcn_mfma_f32_16x16x32_bf16(A[mt][0], B[nt][0], acc, 0, 0, 0);
                acc = __builtin_amdgcn_mfma_f32_16x16x32_bf16(A[mt][1], B[nt][1], acc, 0, 0, 0);
                f32x4 z;
                z[0] = lrelu(acc[0]); z[1] = lrelu(acc[1]);
                z[2] = lrelu(acc[2]); z[3] = lrelu(acc[3]);
                zstore_raw(mt, nt, z);
            }
        }
    };
    gemm_layer(cr.A1, cr.bv0);
    gemm_layer(cr.A2, cr.bv1);
    {
        bf16x8 B[2][2];
#pragma unroll
        for (int nt = 0; nt < 2; nt++)
#pragma unroll
            for (int kt = 0; kt < 2; kt++) B[nt][kt] = ZB(nt, kt);
#pragma unroll
        for (int nt = 0; nt < 2; nt++) {
            f32x4 acc = (f32x4){cr.bz[0], cr.bz[1], cr.bz[2], cr.bz[3]};
            acc = __builtin_amdgcn_mfma_f32_16x16x32_bf16(cr.A3[0], B[nt][0], acc, 0, 0, 0);
            acc = __builtin_amdgcn_mfma_f32_16x16x32_bf16(cr.A3[1], B[nt][1], acc, 0, 0, 0);
            int rowe = R0 + nt * 16 + nl;
            bool valid = (rowe < 780) || (rowe >= 800 && rowe < 840);
            if (valid && rq < 3) {
                int epr = (rowe < 780) ? rowe : rowe - 20;
                float* p = sEP + epr * 10 + rq * 4;
                *(float2*)p = make_float2(acc[0], acc[1]);
                if (rq < 2)
                    *(float2*)(p + 2) = make_float2(acc[2], acc[3]);
            }
        }
    }
}

// ---------------------------------------------------------------------------
// K1 (fused): GCN + MFMA-gather MLP + coalesced X sweep, one graph per block.
// LDS arena (75,320 B, 2 blocks/CU — LDS-limited; VGPR headroom to 256):
//   [0,      8192)  hA   : h in A-frag layout, bf16, k=40..63 zero-padded
//                          | GCN: h0@0 (960 B, below the first pad byte 1280)
//   [8192,  24576)  sBA  : chain-A GEMM ping  | GCN: h1@8192, h2@13312
//   [24576, 40960)  sBB  : chain-B GEMM ping
//   [40960, 73760)  sEP  : 820x10 f32 MLP outputs       | GCN: P@40960
//   [73760, 75320)  sIJ  : edge (i<<8|j) decode table
// hA pad (k>=40, i.e. tiles kt=1 with rq>=1) is zeroed in the prologue so
// GEMM0's K-padding contributes exact 0 (never NaN*0). GCN epilogue writes
// hout (fp32, global) + hA (bf16). Numerics delta vs round 9: E is now
// bf16(h_bf16_i + h_bf16_j) instead of bf16(f32 sum) — <=1 ulp on a path
// that was already bf16-rounded.
// ---------------------------------------------------------------------------
__global__ __launch_bounds__(256, 2) void k_fused(const float* __restrict__ x,
                                                  const float* __restrict__ Wg0,
                                                  const float* __restrict__ bg0,
                                                  const float* __restrict__ Wg1,
                                                  const float* __restrict__ bg1,
                                                  const float* __restrict__ Wg2,
                                                  const float* __restrict__ bg2,
                                                  const unsigned short* __restrict__ wp,
                                                  const float* __restrict__ be0,
                                                  const float* __restrict__ be1,
                                                  const float* __restrict__ be2,
                                                  const float* __restrict__ bn0,
                                                  const float* __restrict__ bn1,
                                                  const float* __restrict__ bn2,
                                                  float* __restrict__ hout,
                                                  float* __restrict__ X) {
    __shared__ __align__(16) char smem[75320];
    unsigned short* hAu = (unsigned short*)smem;             // [0,8192)
    unsigned short* sBA = (unsigned short*)(smem + 8192);    // [8192,24576)
    unsigned short* sBB = (unsigned short*)(smem + 24576);   // [24576,40960)
    float* sEP          = (float*)(smem + 40960);            // [40960,73760)
    unsigned short* sIJ = (unsigned short*)(smem + 73760);   // [73760,75320)
    // GCN-phase aliases
    float* h0  = (float*)smem;                               // [0,960)
    float* h1  = (float*)(smem + 8192);                      // [8192,13312)
    float* h2  = (float*)(smem + 13312);                     // [13312,18432)
    float* P   = (float*)(smem + 40960);                     // [40960,43008)

    const int g = blockIdx.x;
    const int tid = threadIdx.x;
    const int l = tid & 63;
    const int w = tid >> 6;
    const float inv39 = 1.0f / 39.0f;
    const int c32 = tid & 31;
    const int c64 = tid & 63;
    const int rq = (l >> 4) & 3;

    // ---- prologue: edge decode table + hA pad-zero (covered by bar 1..7) --
    for (int m = tid; m < 780; m += 256) {
        float tq = 6241.0f - 8.0f * (float)m;      // exact in fp32
        int i0 = (int)(0.5f * (79.0f - sqrtf(tq)));
        i0 = min(38, max(0, i0));
        int cum = 39 * i0 - ((i0 * (i0 - 1)) >> 1);
        if (cum > m) { --i0; cum = 39 * i0 - ((i0 * (i0 - 1)) >> 1); }
        else if (m - cum >= 39 - i0) { cum += 39 - i0; ++i0; }
        int jj = i0 + 1 + (m - cum);
        sIJ[m] = (unsigned short)((i0 << 8) | jj);
    }
    if (tid < 192) {          // zero hA groups with kt=1, rq>=1 (k=40..63)
        int mt = tid / 48;
        int lz = 16 + (tid % 48);
        us8 z = {};
        *(us8*)((char*)smem + ((mt * 2 + 1) * 64 + lz) * 16) = z;
    }

    // =========================== GCN phase ===========================
    {
        float w0c[6], w1c[32], w2c[32];
#pragma unroll
        for (int f = 0; f < 6; f++)  w0c[f] = Wg0[f * 32 + c32];
#pragma unroll
        for (int m = 0; m < 32; m++) w1c[m] = Wg1[m * 32 + c32];
#pragma unroll
        for (int m = 0; m < 32; m++) w2c[m] = Wg2[m * 64 + c64];
        const float b0c = bg0[c32];
        const float b1c = bg1[c32];
        const float b2c = bg2[c64];

        if (tid < 240) {
            int n = tid / 6, f = tid - n * 6;
            h0[tid] = x[(g * N_NODES + n) * 16 + f];
        }
        __syncthreads();                                      // bar 1

        float breg[10];
        const int n0 = tid >> 5;        // 0..7 (layers 0/1)

        // ---- layer 0 ----
        {
            float psum = 0.f;
#pragma unroll
            for (int t = 0; t < 5; t++) {
                int n = n0 + 8 * t;
                float s = 0.f;
#pragma unroll
                for (int f = 0; f < 6; f++) s += h0[n * 6 + f] * w0c[f];
                breg[t] = s; psum += s;
            }
            P[n0 * 32 + c32] = psum;
        }
        __syncthreads();                                      // bar 2
        {
            float s0 = 0.f;
#pragma unroll
            for (int grp = 0; grp < 8; grp++) s0 += P[grp * 32 + c32];
#pragma unroll
            for (int t = 0; t < 5; t++)
                h1[(n0 + 8 * t) * 32 + c32] = lrelu((s0 - breg[t]) * inv39 + b0c);
        }
        __syncthreads();                                      // bar 3

        // ---- layer 1 ----
        {
            float psum = 0.f;
#pragma unroll
            for (int t = 0; t < 5; t++) {
                int n = n0 + 8 * t;
                const float4* hp = (const float4*)(h1 + n * 32);
                float s = 0.f;
#pragma unroll
                for (int q = 0; q < 8; q++) {
                    float4 hv = hp[q];
                    s += hv.x * w1c[4 * q + 0] + hv.y * w1c[4 * q + 1]
                       + hv.z * w1c[4 * q + 2] + hv.w * w1c[4 * q + 3];
                }
                breg[t] = s; psum += s;
            }
            P[n0 * 32 + c32] = psum;
        }
        __syncthreads();                                      // bar 4
        {
            float s0 = 0.f;
#pragma unroll
            for (int grp = 0; grp < 8; grp++) s0 += P[grp * 32 + c32];
#pragma unroll
            for (int t = 0; t < 5; t++)
                h2[(n0 + 8 * t) * 32 + c32] = lrelu((s0 - breg[t]) * inv39 + b1c);
        }
        __syncthreads();                                      // bar 5

        // ---- layer 2 (64-wide; 10 rows/thread) ----
        const int n02 = tid >> 6;       // 0..3
        {
            float psum = 0.f;
#pragma unroll
            for (int t = 0; t < 10; t++) {
                int n = n02 + 4 * t;
                const float4* hp = (const float4*)(h2 + n * 32);
                float s = 0.f;
#pragma unroll
                for (int q = 0; q < 8; q++) {
                    float4 hv = hp[q];
                    s += hv.x * w2c[4 * q + 0] + hv.y * w2c[4 * q + 1]
                       + hv.z * w2c[4 * q + 2] + hv.w * w2c[4 * q + 3];
                }
                breg[t] = s; psum += s;
            }
            P[n02 * 64 + c64] = psum;
        }
        __syncthreads();                                      // bar 6
        // ---- epilogue: write hout (global, fp32) + hA (LDS, bf16 A-frag) --
        // hA valid entries (k<40) all written here; pad untouched (>=1280 B,
        // h0 occupied only [0,960)).
        {
            float s0 = 0.f;
#pragma unroll
            for (int grp = 0; grp < 4; grp++) s0 += P[grp * 64 + c64];
            const int mt = c64 >> 4, nln = c64 & 15;
#pragma unroll
            for (int t = 0; t < 10; t++) {
                int n = n02 + 4 * t;
                float v = (s0 - breg[t]) * inv39 + b2c;
                hout[g * N_NODES * 64 + n * 64 + c64] = v;
                int kt = n >> 5, rqn = (n >> 3) & 3, jn = n & 7;
                int ln = rqn * 16 + nln;
                hAu[((mt * 2 + kt) * 64 + ln) * 8 + jn] = f2bf(v);
            }
        }
    }
    __syncthreads();   // bar 7: hA + sIJ ready; GCN scratch dead

    // =========================== MLP phase ===========================
    // hoist hA fragments to registers (chunk-invariant; 32 VGPRs)
    bf16x8 hAf[4][2];
#pragma unroll
    for (int mt = 0; mt < 4; mt++)
#pragma unroll
        for (int kt = 0; kt < 2; kt++)
            hAf[mt][kt] = __builtin_bit_cast(bf16x8,
                *(const us8*)(hAu + ((mt * 2 + kt) * 64 + l) * 8));

    auto WA = [&](const unsigned short* base, int mt, int kt) -> bf16x8 {
        return __builtin_bit_cast(bf16x8,
            *(const us8*)(base + ((mt * 2 + kt) * 64 + l) * 8));
    };
    auto loadW = [&](ChunkRegs& cr, const unsigned short* wb,
                     const float* B0, const float* B1, const float* B2) {
#pragma unroll
        for (int mt = 0; mt < 4; mt++) {
#pragma unroll
            for (int kt = 0; kt < 2; kt++) {
                cr.A1[mt][kt] = WA(wb, mt, kt);
                cr.A2[mt][kt] = WA(wb + 4096, mt, kt);
            }
            cr.bv0[mt] = *(const float4*)(B0 + mt * 16 + rq * 4);
            cr.bv1[mt] = *(const float4*)(B1 + mt * 16 + rq * 4);
        }
        cr.A3[0] = WA(wb + 8192, 0, 0);
        cr.A3[1] = WA(wb + 8192, 0, 1);
#pragma unroll
        for (int k = 0; k < 4; k++) {
            int f = rq * 4 + k;
            cr.bz[k] = (f < 10) ? B2[f] : 0.f;
        }
    };

    ChunkRegs ce;
    loadW(ce, wp, be0, be1, be2);            // edge MLP weights

    // balanced chunk map (27 real chunks, no dummy chunk):
    //   wave 0: pairs (0,1)(8,9)(16,17)   + single 24 (edge)
    //   wave 1: pairs (2,3)(10,11)(18,19) + single 25 (node)
    //   wave 2: pairs (4,5)(12,13)(20,21) + single 26 (node)
    //   wave 3: pairs (6,7)(14,15)(22,23)
#pragma unroll
    for (int t = 0; t < 3; t++) {
        int c1 = 2 * w + 8 * t;
        run_pair(32 * c1, 32 * (c1 + 1), w, l, hAf, sBA, sBB, sEP, sIJ, ce);
    }
    if (w == 0) {
        run_single(32 * 24, w, l, hAf, sBA, sEP, sIJ, ce);
    } else if (w == 1) {
        loadW(ce, wp + PACK_PER_MLP, bn0, bn1, bn2);
        run_single(32 * 25, w, l, hAf, sBA, sEP, sIJ, ce);
    } else if (w == 2) {
        loadW(ce, wp + PACK_PER_MLP, bn0, bn1, bn2);
        run_single(32 * 26, w, l, hAf, sBA, sEP, sIJ, ce);
    }

    __syncthreads();   // all EP rows ready

    // ---- X sweep: thread owns whole 4x4 blocks; coalesced stores ----
    float* Xg = X + g * X_PER_G;
#pragma unroll
    for (int k = 0; k < 7; k++) {
        int b = k * 256 + tid;
        if (b < 1600) {
            int bi = b / 40;
            int bj = b - bi * 40;
            int ridx;
            if (bi == bj) {
                ridx = 780 + bi;
            } else {
                int mn = min(bi, bj), mx = max(bi, bj);
                ridx = 39 * mn - ((mn * (mn - 1)) >> 1) + (mx - mn - 1);
            }
            const float* ep = sEP + ridx * 10;
            float2 e0 = *(const float2*)(ep + 0);
            float2 e1 = *(const float2*)(ep + 2);
            float2 e2 = *(const float2*)(ep + 4);
            float2 e3 = *(const float2*)(ep + 6);
            float2 e4 = *(const float2*)(ep + 8);
            float f0 = e0.x, f1 = e0.y, f2 = e1.x, f3 = e1.y;
            float f4 = e2.x, f5 = e2.y, f6 = e3.x, f7 = e3.y;
            float f8 = e4.x, f9 = e4.y;
            float4 r0 = make_float4(f0, f1, f2, f3);
            float4 r1 = make_float4(f1, f4, f5, f6);
            float4 r2 = make_float4(f2, f5, f7, f8);
            float4 r3 = make_float4(f3, f6, f8, f9);
            float* p = Xg + (4 * bi) * X_STRIDE + 4 * bj;
            *(float4*)(p + 0 * X_STRIDE) = r0;
            *(float4*)(p + 1 * X_STRIDE) = r1;
            *(float4*)(p + 2 * X_STRIDE) = r2;
            *(float4*)(p + 3 * X_STRIDE) = r3;
        }
    }
}

// ---------------------------------------------------------------------------
// Launch
// ---------------------------------------------------------------------------
extern "C" void kernel_launch(void* const* d_in, const int* in_sizes, int n_in,
                              void* d_out, int out_size, void* d_ws, size_t ws_size,
                              hipStream_t stream) {
    const float* x   = (const float*)d_in[0];
    const float* Wg0 = (const float*)d_in[4];
    const float* bg0 = (const float*)d_in[5];
    const float* Wg1 = (const float*)d_in[6];
    const float* bg1 = (const float*)d_in[7];
    const float* Wg2 = (const float*)d_in[8];
    const float* bg2 = (const float*)d_in[9];
    const float* Wn0 = (const float*)d_in[10];
    const float* bn0 = (const float*)d_in[11];
    const float* Wn1 = (const float*)d_in[12];
    const float* bn1 = (const float*)d_in[13];
    const float* Wn2 = (const float*)d_in[14];
    const float* bn2 = (const float*)d_in[15];
    const float* We0 = (const float*)d_in[16];
    const float* be0 = (const float*)d_in[17];
    const float* We1 = (const float*)d_in[18];
    const float* be1 = (const float*)d_in[19];
    const float* We2 = (const float*)d_in[20];
    const float* be2 = (const float*)d_in[21];

    float* hout = (float*)d_out;            // h: 40960 x 64 fp32
    float* X    = hout + H_ELEMS;           // X: 1024 x 160 x 160 fp32
    unsigned short* wp = (unsigned short*)d_ws;  // 18432 bf16 packed weights

    k_prep<<<72, 256, 0, stream>>>(We0, We1, We2, Wn0, Wn1, Wn2, wp);
    k_fused<<<G_GRAPHS, 256, 0, stream>>>(x, Wg0, bg0, Wg1, bg1, Wg2, bg2,
                                          wp, be0, be1, be2, bn0, bn1, bn2,
                                          hout, X);
}

// Round 11
// 194.900 us; speedup vs baseline: 1.4343x; 1.0383x over previous
//
#include <hip/hip_runtime.h>

// Problem constants
#define G_GRAPHS 1024
#define N_NODES  40
#define M_EDGES  780          // N*(N-1)/2
#define NUM_NODES (G_GRAPHS * N_NODES)          // 40960
#define H_ELEMS  (NUM_NODES * 64)               // 2621440
#define X_STRIDE 160
#define X_PER_G  25600
#define SLOPE 0.1f

#define PACK_PER_MLP 9216     // W0(4096) + W1(4096) + W2(1024) bf16 elems

typedef __bf16 bf16x8 __attribute__((ext_vector_type(8)));
typedef unsigned short us8 __attribute__((ext_vector_type(8)));
typedef float f32x4 __attribute__((ext_vector_type(4)));

__device__ __forceinline__ float lrelu(float v) { return fmaxf(v, SLOPE * v); }
__device__ __forceinline__ unsigned short f2bf(float x) {
    __bf16 b = (__bf16)x;                       // RNE convert
    return __builtin_bit_cast(unsigned short, b);
}
__device__ __forceinline__ unsigned int pk2bf(float a, float b) {
    return (unsigned int)f2bf(a) | ((unsigned int)f2bf(b) << 16);
}

// ---------------------------------------------------------------------------
// K0: pack MLP weights (bf16) in d_ws. Layout serves the A-frag role:
// element for lane l, reg j, tile (mt,kt) of W^T is
// W[kt*32 + ((l>>4)&3)*8 + j][mt*16 + (l&15)]  -> linear ((mt*2+kt)*64+l)*8+j.
// W2 padded 10->16 cols (zeros). [0..9215] edge MLP, [9216..18431] node MLP.
// ---------------------------------------------------------------------------
__global__ __launch_bounds__(256) void k_prep(const float* __restrict__ We0,
                                              const float* __restrict__ We1,
                                              const float* __restrict__ We2,
                                              const float* __restrict__ Wn0,
                                              const float* __restrict__ Wn1,
                                              const float* __restrict__ Wn2,
                                              unsigned short* __restrict__ wp) {
    int t = blockIdx.x * 256 + threadIdx.x;     // 0..18431 (72 blocks)
    int mlp = t / PACK_PER_MLP;
    int o = t - mlp * PACK_PER_MLP;
    const float* W0 = mlp ? Wn0 : We0;
    const float* W1 = mlp ? Wn1 : We1;
    const float* W2 = mlp ? Wn2 : We2;
    float val;
    if (o < 8192) {
        const float* W = (o < 4096) ? W0 : W1;
        int idx = o & 4095;
        int j = idx & 7, l = (idx >> 3) & 63, tt = idx >> 9;   // tt = mt*2+kt
        int kt = tt & 1, mt = tt >> 1;
        int k = kt * 32 + ((l >> 4) & 3) * 8 + j;
        int m = mt * 16 + (l & 15);
        val = W[k * 64 + m];
    } else {
        int idx = o - 8192;                      // 0..1023, mt=0 only
        int j = idx & 7, l = (idx >> 3) & 63, kt = idx >> 9;
        int k = kt * 32 + ((l >> 4) & 3) * 8 + j;
        int m = l & 15;
        val = (m < 10) ? W2[k * 10 + m] : 0.f;
    }
    wp[mlp * PACK_PER_MLP + o] = f2bf(val);
}

// ---------------------------------------------------------------------------
// MLP machinery. Round-11: DUAL-ACCUMULATE GATHER — GEMM0 + S-build + E
// materialization deleted. Since E@W0 = h_i@W0 + h_j@W0, GEMM1 gathers
// directly: acc = bias; acc += A1.B(h_i); acc += A1.B(h_j), with per-lane
// B-frags read from hB (row-major bf16 h copy, unit-swizzled u^(i&7)).
// Node rows use j=40 (zeroed pad row -> +0 exactly); dummy rows i=j=40.
// MFMA/chunk unchanged (G1 16->32, G0 -16); ~9 LDS ops and TWO serial
// LDS-latency hops removed per chunk. Memory path identical to rounds 5-10.
// ---------------------------------------------------------------------------
struct ChunkRegs {
    bf16x8 A1[4][2];
    bf16x8 A2[4][2];
    bf16x8 A3[2];
    float4 bv0[4];
    float4 bv1[4];
    float  bz[4];
};

__device__ __forceinline__ void dec2(const unsigned short* sIJ, int row,
                                     int& i, int& j) {
    if (row < 780) { int e = sIJ[row]; i = e >> 8; j = e & 255; }
    else if (row >= 800 && row < 840) { i = row - 800; j = 40; }
    else { i = 40; j = 40; }                     // dummy row
}

__device__ __forceinline__ void run_pair(int R0A, int R0B, int w, int l,
                                         const unsigned short* hBu,
                                         unsigned short* sBA,
                                         unsigned short* sBB,
                                         float* sEP,
                                         const unsigned short* sIJ,
                                         const ChunkRegs& cr) {
    const int nl = l & 15;
    const int rq = (l >> 4) & 3;

    // per-lane gather rows (nt=0 -> R0+nl, nt=1 -> R0+16+nl)
    int iA[2], jA[2], iB[2], jB[2];
    dec2(sIJ, R0A + nl, iA[0], jA[0]);
    dec2(sIJ, R0A + 16 + nl, iA[1], jA[1]);
    dec2(sIJ, R0B + nl, iB[0], jB[0]);
    dec2(sIJ, R0B + 16 + nl, iB[1], jB[1]);

    auto BH = [&](int i, int kt) -> bf16x8 {     // h B-frag straight from hB
        int u = (kt * 4 + rq) ^ (i & 7);
        return __builtin_bit_cast(bf16x8, *(const us8*)(hBu + i * 64 + u * 8));
    };
    auto ZB = [&](const unsigned short* s, int nt, int kt) -> bf16x8 {
        int node = 32 * w + nt * 16 + nl;
        int cs = (kt * 4 + rq) ^ (node & 7);
        return __builtin_bit_cast(bf16x8,
            *(const us8*)((const char*)s + node * 128 + cs * 16));
    };
    auto zstore = [&](unsigned short* s, int mt, int nt, const f32x4& v) {
        int node = 32 * w + nt * 16 + nl;
        int cs = (mt * 2 + (rq >> 1)) ^ (node & 7);
        uint2 u = make_uint2(pk2bf(lrelu(v[0]), lrelu(v[1])),
                             pk2bf(lrelu(v[2]), lrelu(v[3])));
        *(uint2*)((char*)s + node * 128 + cs * 16 + (rq & 1) * 8) = u;
    };

    // ---- GEMM1 (gather + layer-0): Z1 = lrelu((h_i+h_j)@W0 + b0) ----
    auto gemm1 = [&](unsigned short* s, const int (&iN)[2], const int (&jN)[2]) {
        bf16x8 Bi[2][2], Bj[2][2];
#pragma unroll
        for (int nt = 0; nt < 2; nt++)
#pragma unroll
            for (int kt = 0; kt < 2; kt++) {
                Bi[nt][kt] = BH(iN[nt], kt);
                Bj[nt][kt] = BH(jN[nt], kt);
            }
#pragma unroll
        for (int mt = 0; mt < 4; mt++) {
            float4 b = cr.bv0[mt];
#pragma unroll
            for (int nt = 0; nt < 2; nt++) {
                f32x4 acc = (f32x4){b.x, b.y, b.z, b.w};   // bias as C-input
                acc = __builtin_amdgcn_mfma_f32_16x16x32_bf16(cr.A1[mt][0], Bi[nt][0], acc, 0, 0, 0);
                acc = __builtin_amdgcn_mfma_f32_16x16x32_bf16(cr.A1[mt][1], Bi[nt][1], acc, 0, 0, 0);
                acc = __builtin_amdgcn_mfma_f32_16x16x32_bf16(cr.A1[mt][0], Bj[nt][0], acc, 0, 0, 0);
                acc = __builtin_amdgcn_mfma_f32_16x16x32_bf16(cr.A1[mt][1], Bj[nt][1], acc, 0, 0, 0);
                zstore(s, mt, nt, acc);
            }
        }
    };
    gemm1(sBA, iA, jA);
    gemm1(sBB, iB, jB);

    // ---- GEMM2: Z2 = lrelu(Z1 @ W1 + b1) -> in place ----
    auto gemm2 = [&](unsigned short* s) {
        bf16x8 B[2][2];
#pragma unroll
        for (int nt = 0; nt < 2; nt++)
#pragma unroll
            for (int kt = 0; kt < 2; kt++) B[nt][kt] = ZB(s, nt, kt);
#pragma unroll
        for (int mt = 0; mt < 4; mt++) {
            float4 b = cr.bv1[mt];
#pragma unroll
            for (int nt = 0; nt < 2; nt++) {
                f32x4 acc = (f32x4){b.x, b.y, b.z, b.w};
                acc = __builtin_amdgcn_mfma_f32_16x16x32_bf16(cr.A2[mt][0], B[nt][0], acc, 0, 0, 0);
                acc = __builtin_amdgcn_mfma_f32_16x16x32_bf16(cr.A2[mt][1], B[nt][1], acc, 0, 0, 0);
                zstore(s, mt, nt, acc);
            }
        }
    };
    gemm2(sBA);
    gemm2(sBB);

    // ---- GEMM3: EP = Z2 @ W2 + b2 -> sEP (f32, stride 10) ----
    auto gemm3 = [&](unsigned short* s, int R0) {
        bf16x8 B[2][2];
#pragma unroll
        for (int nt = 0; nt < 2; nt++)
#pragma unroll
            for (int kt = 0; kt < 2; kt++) B[nt][kt] = ZB(s, nt, kt);
#pragma unroll
        for (int nt = 0; nt < 2; nt++) {
            f32x4 acc = (f32x4){cr.bz[0], cr.bz[1], cr.bz[2], cr.bz[3]};
            acc = __builtin_amdgcn_mfma_f32_16x16x32_bf16(cr.A3[0], B[nt][0], acc, 0, 0, 0);
            acc = __builtin_amdgcn_mfma_f32_16x16x32_bf16(cr.A3[1], B[nt][1], acc, 0, 0, 0);
            int rowe = R0 + nt * 16 + nl;
            bool valid = (rowe < 780) || (rowe >= 800 && rowe < 840);
            if (valid && rq < 3) {
                int epr = (rowe < 780) ? rowe : rowe - 20;   // nodes -> 780..819
                float* p = sEP + epr * 10 + rq * 4;
                *(float2*)p = make_float2(acc[0], acc[1]);
                if (rq < 2)
                    *(float2*)(p + 2) = make_float2(acc[2], acc[3]);
            }
        }
    };
    gemm3(sBA, R0A);
    gemm3(sBB, R0B);
}

// single-chain chunk (uses the wave's sBA slice only)
__device__ __forceinline__ void run_single(int R0, int w, int l,
                                           const unsigned short* hBu,
                                           unsigned short* sBA,
                                           float* sEP,
                                           const unsigned short* sIJ,
                                           const ChunkRegs& cr) {
    const int nl = l & 15;
    const int rq = (l >> 4) & 3;

    int iN[2], jN[2];
    dec2(sIJ, R0 + nl, iN[0], jN[0]);
    dec2(sIJ, R0 + 16 + nl, iN[1], jN[1]);

    auto BH = [&](int i, int kt) -> bf16x8 {
        int u = (kt * 4 + rq) ^ (i & 7);
        return __builtin_bit_cast(bf16x8, *(const us8*)(hBu + i * 64 + u * 8));
    };
    auto ZB = [&](int nt, int kt) -> bf16x8 {
        int node = 32 * w + nt * 16 + nl;
        int cs = (kt * 4 + rq) ^ (node & 7);
        return __builtin_bit_cast(bf16x8,
            *(const us8*)((const char*)sBA + node * 128 + cs * 16));
    };
    auto zstore = [&](int mt, int nt, const f32x4& v) {
        int node = 32 * w + nt * 16 + nl;
        int cs = (mt * 2 + (rq >> 1)) ^ (node & 7);
        uint2 u = make_uint2(pk2bf(lrelu(v[0]), lrelu(v[1])),
                             pk2bf(lrelu(v[2]), lrelu(v[3])));
        *(uint2*)((char*)sBA + node * 128 + cs * 16 + (rq & 1) * 8) = u;
    };

    // GEMM1 (gather + layer-0)
    {
        bf16x8 Bi[2][2], Bj[2][2];
#pragma unroll
        for (int nt = 0; nt < 2; nt++)
#pragma unroll
            for (int kt = 0; kt < 2; kt++) {
                Bi[nt][kt] = BH(iN[nt], kt);
                Bj[nt][kt] = BH(jN[nt], kt);
            }
#pragma unroll
        for (int mt = 0; mt < 4; mt++) {
            float4 b = cr.bv0[mt];
#pragma unroll
            for (int nt = 0; nt < 2; nt++) {
                f32x4 acc = (f32x4){b.x, b.y, b.z, b.w};
                acc = __builtin_amdgcn_mfma_f32_16x16x32_bf16(cr.A1[mt][0], Bi[nt][0], acc, 0, 0, 0);
                acc = __builtin_amdgcn_mfma_f32_16x16x32_bf16(cr.A1[mt][1], Bi[nt][1], acc, 0, 0, 0);
                acc = __builtin_amdgcn_mfma_f32_16x16x32_bf16(cr.A1[mt][0], Bj[nt][0], acc, 0, 0, 0);
                acc = __builtin_amdgcn_mfma_f32_16x16x32_bf16(cr.A1[mt][1], Bj[nt][1], acc, 0, 0, 0);
                zstore(mt, nt, acc);
            }
        }
    }
    // GEMM2
    {
        bf16x8 B[2][2];
#pragma unroll
        for (int nt = 0; nt < 2; nt++)
#pragma unroll
            for (int kt = 0; kt < 2; kt++) B[nt][kt] = ZB(nt, kt);
#pragma unroll
        for (int mt = 0; mt < 4; mt++) {
            float4 b = cr.bv1[mt];
#pragma unroll
            for (int nt = 0; nt < 2; nt++) {
                f32x4 acc = (f32x4){b.x, b.y, b.z, b.w};
                acc = __builtin_amdgcn_mfma_f32_16x16x32_bf16(cr.A2[mt][0], B[nt][0], acc, 0, 0, 0);
                acc = __builtin_amdgcn_mfma_f32_16x16x32_bf16(cr.A2[mt][1], B[nt][1], acc, 0, 0, 0);
                zstore(mt, nt, acc);
            }
        }
    }
    // GEMM3
    {
        bf16x8 B[2][2];
#pragma unroll
        for (int nt = 0; nt < 2; nt++)
#pragma unroll
            for (int kt = 0; kt < 2; kt++) B[nt][kt] = ZB(nt, kt);
#pragma unroll
        for (int nt = 0; nt < 2; nt++) {
            f32x4 acc = (f32x4){cr.bz[0], cr.bz[1], cr.bz[2], cr.bz[3]};
            acc = __builtin_amdgcn_mfma_f32_16x16x32_bf16(cr.A3[0], B[nt][0], acc, 0, 0, 0);
            acc = __builtin_amdgcn_mfma_f32_16x16x32_bf16(cr.A3[1], B[nt][1], acc, 0, 0, 0);
            int rowe = R0 + nt * 16 + nl;
            bool valid = (rowe < 780) || (rowe >= 800 && rowe < 840);
            if (valid && rq < 3) {
                int epr = (rowe < 780) ? rowe : rowe - 20;
                float* p = sEP + epr * 10 + rq * 4;
                *(float2*)p = make_float2(acc[0], acc[1]);
                if (rq < 2)
                    *(float2*)(p + 2) = make_float2(acc[2], acc[3]);
            }
        }
    }
}

// ---------------------------------------------------------------------------
// K1 (fused): GCN + dual-gather MLP + coalesced X sweep, one graph per block.
// LDS arena (73,376 B, 2 blocks/CU):
//   [0,      6144)  hB   : h bf16, 48 rows x 64, unit-swizzled u^(i&7);
//                          rows 40..47 zeroed (node/dummy j-gather target)
//                          | GCN: h0@0 (960 B; dead before epilogue writes)
//   [6144,   7704)  sIJ  : edge (i<<8|j) decode table
//   [7808,  24192)  sBA  : chain-A Z1/Z2 ping  | GCN: h1@7808, h2@12928
//   [24192, 40576)  sBB  : chain-B Z1/Z2 ping
//   [40576, 73376)  sEP  : 820x10 f32 MLP outputs   | GCN: P@40576
// ---------------------------------------------------------------------------
__global__ __launch_bounds__(256, 2) void k_fused(const float* __restrict__ x,
                                                  const float* __restrict__ Wg0,
                                                  const float* __restrict__ bg0,
                                                  const float* __restrict__ Wg1,
                                                  const float* __restrict__ bg1,
                                                  const float* __restrict__ Wg2,
                                                  const float* __restrict__ bg2,
                                                  const unsigned short* __restrict__ wp,
                                                  const float* __restrict__ be0,
                                                  const float* __restrict__ be1,
                                                  const float* __restrict__ be2,
                                                  const float* __restrict__ bn0,
                                                  const float* __restrict__ bn1,
                                                  const float* __restrict__ bn2,
                                                  float* __restrict__ hout,
                                                  float* __restrict__ X) {
    __shared__ __align__(16) char smem[73376];
    unsigned short* hBu = (unsigned short*)smem;             // [0,6144)
    unsigned short* sIJ = (unsigned short*)(smem + 6144);    // [6144,7704)
    unsigned short* sBA = (unsigned short*)(smem + 7808);    // [7808,24192)
    unsigned short* sBB = (unsigned short*)(smem + 24192);   // [24192,40576)
    float* sEP          = (float*)(smem + 40576);            // [40576,73376)
    // GCN-phase aliases
    float* h0  = (float*)smem;                               // [0,960)
    float* h1  = (float*)(smem + 7808);                      // [7808,12928)
    float* h2  = (float*)(smem + 12928);                     // [12928,18048)
    float* P   = (float*)(smem + 40576);                     // [40576,42624)

    const int g = blockIdx.x;
    const int tid = threadIdx.x;
    const int l = tid & 63;
    const int w = tid >> 6;
    const float inv39 = 1.0f / 39.0f;
    const int c32 = tid & 31;
    const int c64 = tid & 63;
    const int rq = (l >> 4) & 3;

    // ---- prologue: edge decode table + hB pad rows 40..47 zeroed ----
    for (int m = tid; m < 780; m += 256) {
        float tq = 6241.0f - 8.0f * (float)m;      // exact in fp32
        int i0 = (int)(0.5f * (79.0f - sqrtf(tq)));
        i0 = min(38, max(0, i0));
        int cum = 39 * i0 - ((i0 * (i0 - 1)) >> 1);
        if (cum > m) { --i0; cum = 39 * i0 - ((i0 * (i0 - 1)) >> 1); }
        else if (m - cum >= 39 - i0) { cum += 39 - i0; ++i0; }
        int jj = i0 + 1 + (m - cum);
        sIJ[m] = (unsigned short)((i0 << 8) | jj);
    }
    if (tid < 64) {                    // rows 40..47: 8 rows x 8 us8 units
        us8 z = {};
        *(us8*)(hBu + (40 + (tid >> 3)) * 64 + (tid & 7) * 8) = z;
    }

    // =========================== GCN phase ===========================
    {
        float w0c[6], w1c[32], w2c[32];
#pragma unroll
        for (int f = 0; f < 6; f++)  w0c[f] = Wg0[f * 32 + c32];
#pragma unroll
        for (int m = 0; m < 32; m++) w1c[m] = Wg1[m * 32 + c32];
#pragma unroll
        for (int m = 0; m < 32; m++) w2c[m] = Wg2[m * 64 + c64];
        const float b0c = bg0[c32];
        const float b1c = bg1[c32];
        const float b2c = bg2[c64];

        if (tid < 240) {
            int n = tid / 6, f = tid - n * 6;
            h0[tid] = x[(g * N_NODES + n) * 16 + f];
        }
        __syncthreads();                                      // bar 1

        float breg[10];
        const int n0 = tid >> 5;        // 0..7 (layers 0/1)

        // ---- layer 0 ----
        {
            float psum = 0.f;
#pragma unroll
            for (int t = 0; t < 5; t++) {
                int n = n0 + 8 * t;
                float s = 0.f;
#pragma unroll
                for (int f = 0; f < 6; f++) s += h0[n * 6 + f] * w0c[f];
                breg[t] = s; psum += s;
            }
            P[n0 * 32 + c32] = psum;
        }
        __syncthreads();                                      // bar 2
        {
            float s0 = 0.f;
#pragma unroll
            for (int grp = 0; grp < 8; grp++) s0 += P[grp * 32 + c32];
#pragma unroll
            for (int t = 0; t < 5; t++)
                h1[(n0 + 8 * t) * 32 + c32] = lrelu((s0 - breg[t]) * inv39 + b0c);
        }
        __syncthreads();                                      // bar 3

        // ---- layer 1 ----
        {
            float psum = 0.f;
#pragma unroll
            for (int t = 0; t < 5; t++) {
                int n = n0 + 8 * t;
                const float4* hp = (const float4*)(h1 + n * 32);
                float s = 0.f;
#pragma unroll
                for (int q = 0; q < 8; q++) {
                    float4 hv = hp[q];
                    s += hv.x * w1c[4 * q + 0] + hv.y * w1c[4 * q + 1]
                       + hv.z * w1c[4 * q + 2] + hv.w * w1c[4 * q + 3];
                }
                breg[t] = s; psum += s;
            }
            P[n0 * 32 + c32] = psum;
        }
        __syncthreads();                                      // bar 4
        {
            float s0 = 0.f;
#pragma unroll
            for (int grp = 0; grp < 8; grp++) s0 += P[grp * 32 + c32];
#pragma unroll
            for (int t = 0; t < 5; t++)
                h2[(n0 + 8 * t) * 32 + c32] = lrelu((s0 - breg[t]) * inv39 + b1c);
        }
        __syncthreads();                                      // bar 5

        // ---- layer 2 (64-wide; 10 rows/thread) ----
        const int n02 = tid >> 6;       // 0..3
        {
            float psum = 0.f;
#pragma unroll
            for (int t = 0; t < 10; t++) {
                int n = n02 + 4 * t;
                const float4* hp = (const float4*)(h2 + n * 32);
                float s = 0.f;
#pragma unroll
                for (int q = 0; q < 8; q++) {
                    float4 hv = hp[q];
                    s += hv.x * w2c[4 * q + 0] + hv.y * w2c[4 * q + 1]
                       + hv.z * w2c[4 * q + 2] + hv.w * w2c[4 * q + 3];
                }
                breg[t] = s; psum += s;
            }
            P[n02 * 64 + c64] = psum;
        }
        __syncthreads();                                      // bar 6
        // ---- epilogue: write hout (global, fp32) + hB (LDS, bf16) ----
        // hB row n, unit u = (c64>>3)^(n&7), elem c64&7. h0 dead.
        {
            float s0 = 0.f;
#pragma unroll
            for (int grp = 0; grp < 4; grp++) s0 += P[grp * 64 + c64];
#pragma unroll
            for (int t = 0; t < 10; t++) {
                int n = n02 + 4 * t;
                float v = (s0 - breg[t]) * inv39 + b2c;
                hout[g * N_NODES * 64 + n * 64 + c64] = v;
                int u = (c64 >> 3) ^ (n & 7);
                hBu[n * 64 + u * 8 + (c64 & 7)] = f2bf(v);
            }
        }
    }
    __syncthreads();   // bar 7: hB + sIJ ready; GCN scratch dead

    // =========================== MLP phase ===========================
    auto WA = [&](const unsigned short* base, int mt, int kt) -> bf16x8 {
        return __builtin_bit_cast(bf16x8,
            *(const us8*)(base + ((mt * 2 + kt) * 64 + l) * 8));
    };
    auto loadW = [&](ChunkRegs& cr, const unsigned short* wb,
                     const float* B0, const float* B1, const float* B2) {
#pragma unroll
        for (int mt = 0; mt < 4; mt++) {
#pragma unroll
            for (int kt = 0; kt < 2; kt++) {
                cr.A1[mt][kt] = WA(wb, mt, kt);
                cr.A2[mt][kt] = WA(wb + 4096, mt, kt);
            }
            cr.bv0[mt] = *(const float4*)(B0 + mt * 16 + rq * 4);
            cr.bv1[mt] = *(const float4*)(B1 + mt * 16 + rq * 4);
        }
        cr.A3[0] = WA(wb + 8192, 0, 0);
        cr.A3[1] = WA(wb + 8192, 0, 1);
#pragma unroll
        for (int k = 0; k < 4; k++) {
            int f = rq * 4 + k;
            cr.bz[k] = (f < 10) ? B2[f] : 0.f;
        }
    };

    ChunkRegs ce;
    loadW(ce, wp, be0, be1, be2);            // edge MLP weights

    // balanced chunk map (27 real chunks, no dummy chunk):
    //   wave 0: pairs (0,1)(8,9)(16,17)   + single 24 (edge)
    //   wave 1: pairs (2,3)(10,11)(18,19) + single 25 (node)
    //   wave 2: pairs (4,5)(12,13)(20,21) + single 26 (node)
    //   wave 3: pairs (6,7)(14,15)(22,23)
#pragma unroll
    for (int t = 0; t < 3; t++) {
        int c1 = 2 * w + 8 * t;
        run_pair(32 * c1, 32 * (c1 + 1), w, l, hBu, sBA, sBB, sEP, sIJ, ce);
    }
    if (w == 0) {
        run_single(32 * 24, w, l, hBu, sBA, sEP, sIJ, ce);
    } else if (w == 1) {
        loadW(ce, wp + PACK_PER_MLP, bn0, bn1, bn2);
        run_single(32 * 25, w, l, hBu, sBA, sEP, sIJ, ce);
    } else if (w == 2) {
        loadW(ce, wp + PACK_PER_MLP, bn0, bn1, bn2);
        run_single(32 * 26, w, l, hBu, sBA, sEP, sIJ, ce);
    }

    __syncthreads();   // all EP rows ready

    // ---- X sweep: thread owns whole 4x4 blocks; coalesced stores ----
    float* Xg = X + g * X_PER_G;
#pragma unroll
    for (int k = 0; k < 7; k++) {
        int b = k * 256 + tid;
        if (b < 1600) {
            int bi = b / 40;
            int bj = b - bi * 40;
            int ridx;
            if (bi == bj) {
                ridx = 780 + bi;
            } else {
                int mn = min(bi, bj), mx = max(bi, bj);
                ridx = 39 * mn - ((mn * (mn - 1)) >> 1) + (mx - mn - 1);
            }
            const float* ep = sEP + ridx * 10;
            float2 e0 = *(const float2*)(ep + 0);
            float2 e1 = *(const float2*)(ep + 2);
            float2 e2 = *(const float2*)(ep + 4);
            float2 e3 = *(const float2*)(ep + 6);
            float2 e4 = *(const float2*)(ep + 8);
            float f0 = e0.x, f1 = e0.y, f2 = e1.x, f3 = e1.y;
            float f4 = e2.x, f5 = e2.y, f6 = e3.x, f7 = e3.y;
            float f8 = e4.x, f9 = e4.y;
            float4 r0 = make_float4(f0, f1, f2, f3);
            float4 r1 = make_float4(f1, f4, f5, f6);
            float4 r2 = make_float4(f2, f5, f7, f8);
            float4 r3 = make_float4(f3, f6, f8, f9);
            float* p = Xg + (4 * bi) * X_STRIDE + 4 * bj;
            *(float4*)(p + 0 * X_STRIDE) = r0;
            *(float4*)(p + 1 * X_STRIDE) = r1;
            *(float4*)(p + 2 * X_STRIDE) = r2;
            *(float4*)(p + 3 * X_STRIDE) = r3;
        }
    }
}

// ---------------------------------------------------------------------------
// Launch
// ---------------------------------------------------------------------------
extern "C" void kernel_launch(void* const* d_in, const int* in_sizes, int n_in,
                              void* d_out, int out_size, void* d_ws, size_t ws_size,
                              hipStream_t stream) {
    const float* x   = (const float*)d_in[0];
    const float* Wg0 = (const float*)d_in[4];
    const float* bg0 = (const float*)d_in[5];
    const float* Wg1 = (const float*)d_in[6];
    const float* bg1 = (const float*)d_in[7];
    const float* Wg2 = (const float*)d_in[8];
    const float* bg2 = (const float*)d_in[9];
    const float* Wn0 = (const float*)d_in[10];
    const float* bn0 = (const float*)d_in[11];
    const float* Wn1 = (const float*)d_in[12];
    const float* bn1 = (const float*)d_in[13];
    const float* Wn2 = (const float*)d_in[14];
    const float* bn2 = (const float*)d_in[15];
    const float* We0 = (const float*)d_in[16];
    const float* be0 = (const float*)d_in[17];
    const float* We1 = (const float*)d_in[18];
    const float* be1 = (const float*)d_in[19];
    const float* We2 = (const float*)d_in[20];
    const float* be2 = (const float*)d_in[21];

    float* hout = (float*)d_out;            // h: 40960 x 64 fp32
    float* X    = hout + H_ELEMS;           // X: 1024 x 160 x 160 fp32
    unsigned short* wp = (unsigned short*)d_ws;  // 18432 bf16 packed weights

    k_prep<<<72, 256, 0, stream>>>(We0, We1, We2, Wn0, Wn1, Wn2, wp);
    k_fused<<<G_GRAPHS, 256, 0, stream>>>(x, Wg0, bg0, Wg1, bg1, Wg2, bg2,
                                          wp, be0, be1, be2, bn0, bn1, bn2,
                                          hout, X);
}